// Round 15
// baseline (207.324 us; speedup 1.0000x reference)
//
#include <hip/hip_runtime.h>
#include <hip/hip_bf16.h>

#define NWN    100000   // word nodes
#define NTN    1600     // topic nodes
#define NDOC   16384
#define EWD    1000000
#define ETD    200000
#define NWORD  15000
#define NTOPIC 50
#define HD     128
#define NB     32       // graphs

// --- 1) degree counts for both relations -----------------------------------
__global__ void p_degrees(const int* __restrict__ wd_src, const int* __restrict__ wd_dst,
                          const int* __restrict__ td_src, const int* __restrict__ td_dst,
                          float* __restrict__ deg_w, float* __restrict__ deg_dwd,
                          float* __restrict__ deg_t, float* __restrict__ deg_dtd) {
    int i = blockIdx.x * blockDim.x + threadIdx.x;
    if (i < EWD) {
        atomicAdd(deg_w   + wd_src[i], 1.0f);
        atomicAdd(deg_dwd + wd_dst[i], 1.0f);
    } else if (i < EWD + ETD) {
        int e = i - EWD;
        atomicAdd(deg_t   + td_src[e], 1.0f);
        atomicAdd(deg_dtd + td_dst[e], 1.0f);
    }
}

// --- 2) v_wd = W_wd @ W_out, v_td = W_td @ W_out ----------------------------
__global__ void p_v(const float* __restrict__ Wwd,
                    const float* __restrict__ Wtd,
                    const float* __restrict__ Wout,
                    float* __restrict__ v_wd, float* __restrict__ v_td) {
    __shared__ float wout[HD];
    int t = threadIdx.x;              // 128 threads
    wout[t] = Wout[t];
    __syncthreads();
    float s1 = 0.f, s2 = 0.f;
    for (int j = 0; j < HD; ++j) {
        s1 += Wwd[t * HD + j] * wout[j];
        s2 += Wtd[t * HD + j] * wout[j];
    }
    v_wd[t] = s1;
    v_td[t] = s2;
}

// --- 3) u_wd[wid] = word_embeds[wid] . v_wd ; u_td likewise (wave per row) --
__global__ void p_u(const float* __restrict__ wemb,
                    const float* __restrict__ temb,
                    const float* __restrict__ v_wd, const float* __restrict__ v_td,
                    float* __restrict__ u_wd, float* __restrict__ u_td) {
    int wave = threadIdx.x >> 6;
    int lane = threadIdx.x & 63;
    int row  = blockIdx.x * (blockDim.x >> 6) + wave;
    const float* src; const float* v; float* dst; int r;
    if (row < NWORD)               { src = wemb; v = v_wd; dst = u_wd; r = row; }
    else if (row < NWORD + NTOPIC) { src = temb; v = v_td; dst = u_td; r = row - NWORD; }
    else return;
    float s = src[r * HD + lane]      * v[lane]
            + src[r * HD + lane + 64] * v[lane + 64];
    #pragma unroll
    for (int off = 32; off; off >>= 1) s += __shfl_down(s, off);
    if (lane == 0) dst[r] = s;
}

// --- 4) per-node scalar with outdeg normalization ---------------------------
__global__ void p_unode(const int* __restrict__ word_ids, const int* __restrict__ topic_ids,
                        const float* __restrict__ deg_w, const float* __restrict__ deg_t,
                        const float* __restrict__ u_wd, const float* __restrict__ u_td,
                        float* __restrict__ un_w, float* __restrict__ un_t) {
    int i = blockIdx.x * blockDim.x + threadIdx.x;
    if (i < NWN) {
        un_w[i] = u_wd[word_ids[i]] * rsqrtf(fmaxf(deg_w[i], 1.0f));
    } else if (i < NWN + NTN) {
        int j = i - NWN;
        un_t[j] = u_td[topic_ids[j]] * rsqrtf(fmaxf(deg_t[j], 1.0f));
    }
}

// --- 5) per-edge scalar accumulation into 32 graph slots --------------------
__global__ void p_edges(const int* __restrict__ wd_src, const int* __restrict__ wd_dst,
                        const int* __restrict__ td_src, const int* __restrict__ td_dst,
                        const float* __restrict__ un_w, const float* __restrict__ un_t,
                        const float* __restrict__ deg_dwd, const float* __restrict__ deg_dtd,
                        float* __restrict__ acc) {
    __shared__ float lacc[NB];
    if (threadIdx.x < NB) lacc[threadIdx.x] = 0.f;
    __syncthreads();
    const int total = EWD + ETD;
    for (int i = blockIdx.x * blockDim.x + threadIdx.x; i < total;
         i += gridDim.x * blockDim.x) {
        int dst; float val;
        if (i < EWD) {
            dst = wd_dst[i];
            val = un_w[wd_src[i]] * rsqrtf(fmaxf(deg_dwd[dst], 1.0f));
        } else {
            int e = i - EWD;
            dst = td_dst[e];
            val = un_t[td_src[e]] * rsqrtf(fmaxf(deg_dtd[dst], 1.0f));
        }
        atomicAdd(&lacc[dst >> 9], val);   // graph id = dst / 512
    }
    __syncthreads();
    if (threadIdx.x < NB) atomicAdd(acc + threadIdx.x, lacc[threadIdx.x]);
}

// --- 6) finalize: FLOAT32 output — loss at out[0], y_pred at out[1..32] -----
__global__ void p_final(const float* __restrict__ acc,
                        const float* __restrict__ y_data,
                        const float* __restrict__ b_wd,
                        const float* __restrict__ b_td,
                        const float* __restrict__ Wout,
                        const float* __restrict__ b_out,
                        float* __restrict__ out) {
    __shared__ float red[2];
    __shared__ float c0s;
    __shared__ float lsum[NB];
    int t = threadIdx.x;              // 128 threads
    float p = (b_wd[t] + b_td[t]) * Wout[t];
    #pragma unroll
    for (int off = 32; off; off >>= 1) p += __shfl_down(p, off);
    if ((t & 63) == 0) red[t >> 6] = p;
    __syncthreads();
    if (t == 0) c0s = red[0] + red[1] + b_out[0];
    __syncthreads();
    float c0 = c0s;
    if (t < NB) {
        float x = acc[t] * (1.0f / 512.0f) + c0;
        float y = y_data[t];
        lsum[t] = fmaxf(x, 0.f) - x * y + log1pf(expf(-fabsf(x)));
        out[1 + t] = 1.0f / (1.0f + expf(-x));     // y_pred (f32!)
    }
    __syncthreads();
    if (t == 0) {
        float s = 0.f;
        #pragma unroll
        for (int i = 0; i < NB; ++i) s += lsum[i];
        out[0] = s / (float)NB;                    // loss (f32!)
    }
}

extern "C" void kernel_launch(void* const* d_in, const int* in_sizes, int n_in,
                              void* d_out, int out_size, void* d_ws, size_t ws_size,
                              hipStream_t stream) {
    // inputs: setup_inputs() dict order, all floats are f32 (confirmed R1/R8)
    const int* word_ids  = (const int*)d_in[0];
    const int* topic_ids = (const int*)d_in[1];
    const int* wd_src    = (const int*)d_in[2];
    const int* wd_dst    = (const int*)d_in[3];
    const int* td_src    = (const int*)d_in[4];
    const int* td_dst    = (const int*)d_in[5];
    const float* y_data  = (const float*)d_in[6];
    const float* wemb    = (const float*)d_in[7];
    const float* temb    = (const float*)d_in[8];
    const float* Wwd     = (const float*)d_in[9];
    const float* bwd     = (const float*)d_in[10];
    const float* Wtd     = (const float*)d_in[11];
    const float* btd     = (const float*)d_in[12];
    const float* Wout    = (const float*)d_in[13];
    const float* bout    = (const float*)d_in[14];
    float* out = (float*)d_out;          // reference output dtype is FLOAT32

    float* ws      = (float*)d_ws;
    float* deg_w   = ws;                 // NWN
    float* deg_t   = deg_w   + NWN;      // NTN
    float* deg_dwd = deg_t   + NTN;      // NDOC
    float* deg_dtd = deg_dwd + NDOC;     // NDOC
    float* u_wd    = deg_dtd + NDOC;     // NWORD
    float* u_td    = u_wd    + NWORD;    // 64 (padded)
    float* un_w    = u_td    + 64;       // NWN
    float* un_t    = un_w    + NWN;      // NTN
    float* v_wd    = un_t    + NTN;      // 128
    float* v_td    = v_wd    + 128;      // 128
    float* acc     = v_td    + 128;      // NB

    // zero degree counters and the logit accumulator (ws is poisoned 0xAA)
    hipMemsetAsync(ws, 0, (size_t)(NWN + NTN + 2 * NDOC) * sizeof(float), stream);
    hipMemsetAsync(acc, 0, NB * sizeof(float), stream);

    {   // degrees over both edge sets
        int total = EWD + ETD;
        p_degrees<<<(total + 255) / 256, 256, 0, stream>>>(
            wd_src, wd_dst, td_src, td_dst, deg_w, deg_dwd, deg_t, deg_dtd);
    }
    p_v<<<1, HD, 0, stream>>>(Wwd, Wtd, Wout, v_wd, v_td);
    {   // one wave per embedding row
        int rows = NWORD + NTOPIC;
        p_u<<<(rows + 3) / 4, 256, 0, stream>>>(wemb, temb, v_wd, v_td, u_wd, u_td);
    }
    {
        int total = NWN + NTN;
        p_unode<<<(total + 255) / 256, 256, 0, stream>>>(
            word_ids, topic_ids, deg_w, deg_t, u_wd, u_td, un_w, un_t);
    }
    p_edges<<<2048, 256, 0, stream>>>(wd_src, wd_dst, td_src, td_dst,
                                      un_w, un_t, deg_dwd, deg_dtd, acc);
    p_final<<<1, HD, 0, stream>>>(acc, y_data, bwd, btd, Wout, bout, out);
}

// Round 16
// 151.867 us; speedup vs baseline: 1.3652x; 1.3652x over previous
//
#include <hip/hip_runtime.h>
#include <hip/hip_bf16.h>

#define NWN    100000   // word nodes
#define NTN    1600     // topic nodes
#define NDOC   16384
#define EWD    1000000
#define ETD    200000
#define NWORD  15000
#define NTOPIC 50
#define HD     128
#define NB     32       // graphs
#define DSTRIDE 4       // doc counter stride (u32 units): 4 counters / 64B line
#define TSTRIDE 16      // topic counter stride: 1 counter / 64B line

// ws word layout:
//   deg_w  [0, 100000)                    dense u32
//   docs   [100000, 100000+65536)         packed u32 (wd lo16 | td hi16), stride 4
//   deg_t  [165536, 165536+25600)         u32, stride 16
//   acc    [191136, 191168)               f32[32]
//   v      [191168, 191424)               f32[256] (v_wd | v_td)
//   u_wd   [191424, 206424)               f32[15000]
//   u_td   [206424, 206488)               f32[50 pad 64]
#define OFF_DOCS 100000
#define OFF_DEGT 165536
#define OFF_ACC  191136
#define NZWORDS  191168   // zero region (degrees + acc)

// --- 1) degree counts: strided/packed uint atomics --------------------------
__global__ void d_deg(const int* __restrict__ wd_src, const int* __restrict__ wd_dst,
                      const int* __restrict__ td_src, const int* __restrict__ td_dst,
                      unsigned* __restrict__ wsbase) {
    unsigned* deg_w = wsbase;
    unsigned* docs  = wsbase + OFF_DOCS;
    unsigned* deg_t = wsbase + OFF_DEGT;
    int i = blockIdx.x * blockDim.x + threadIdx.x;
    if (i < EWD) {
        atomicAdd(deg_w + wd_src[i], 1u);
        atomicAdd(docs + wd_dst[i] * DSTRIDE, 1u);        // low 16 bits
    } else if (i < EWD + ETD) {
        int e = i - EWD;
        atomicAdd(deg_t + td_src[e] * TSTRIDE, 1u);
        atomicAdd(docs + td_dst[e] * DSTRIDE, 65536u);    // high 16 bits
    }
}

// --- 2) v_wd = W_wd @ W_out, v_td = W_td @ W_out ----------------------------
__global__ void d_v(const float* __restrict__ Wwd,
                    const float* __restrict__ Wtd,
                    const float* __restrict__ Wout,
                    float* __restrict__ v) {
    __shared__ float wout[HD];
    int t = threadIdx.x;              // 128 threads
    wout[t] = Wout[t];
    __syncthreads();
    float s1 = 0.f, s2 = 0.f;
    for (int j = 0; j < HD; ++j) {
        s1 += Wwd[t * HD + j] * wout[j];
        s2 += Wtd[t * HD + j] * wout[j];
    }
    v[t]      = s1;
    v[t + HD] = s2;
}

// --- 3) u[row] = emb_row . v  (one wave per row) -----------------------------
__global__ void d_u(const float* __restrict__ wemb,
                    const float* __restrict__ temb,
                    const float* __restrict__ v,
                    float* __restrict__ u_wd, float* __restrict__ u_td) {
    int wave = threadIdx.x >> 6;
    int lane = threadIdx.x & 63;
    int row  = blockIdx.x * (blockDim.x >> 6) + wave;
    const float* src; const float* vv; float* dst; int r;
    if (row < NWORD)               { src = wemb; vv = v;      dst = u_wd; r = row; }
    else if (row < NWORD + NTOPIC) { src = temb; vv = v + HD; dst = u_td; r = row - NWORD; }
    else return;
    float s = src[r * HD + lane]      * vv[lane]
            + src[r * HD + lane + 64] * vv[lane + 64];
    #pragma unroll
    for (int off = 32; off; off >>= 1) s += __shfl_down(s, off);
    if (lane == 0) dst[r] = s;
}

// --- 4) per-edge scalar with all norms fused; LDS acc -> global acc ---------
__global__ void d_edges(const int* __restrict__ wd_src, const int* __restrict__ wd_dst,
                        const int* __restrict__ td_src, const int* __restrict__ td_dst,
                        const int* __restrict__ wids, const int* __restrict__ tids,
                        const unsigned* __restrict__ wsbase,
                        const float* __restrict__ u_wd, const float* __restrict__ u_td,
                        float* __restrict__ acc) {
    const unsigned* deg_w = wsbase;
    const unsigned* docs  = wsbase + OFF_DOCS;
    const unsigned* deg_t = wsbase + OFF_DEGT;
    __shared__ float lacc[NB];
    if (threadIdx.x < NB) lacc[threadIdx.x] = 0.f;
    __syncthreads();
    const int total = EWD + ETD;
    for (int i = blockIdx.x * blockDim.x + threadIdx.x; i < total;
         i += gridDim.x * blockDim.x) {
        int d; float val;
        if (i < EWD) {
            int s = wd_src[i]; d = wd_dst[i];
            unsigned a = deg_w[s];
            unsigned b = docs[d * DSTRIDE] & 0xFFFFu;
            val = u_wd[wids[s]] * rsqrtf((float)(a > 1u ? a : 1u))
                                * rsqrtf((float)(b > 1u ? b : 1u));
        } else {
            int e = i - EWD;
            int s = td_src[e]; d = td_dst[e];
            unsigned a = deg_t[s * TSTRIDE];
            unsigned b = docs[d * DSTRIDE] >> 16;
            val = u_td[tids[s]] * rsqrtf((float)(a > 1u ? a : 1u))
                               * rsqrtf((float)(b > 1u ? b : 1u));
        }
        atomicAdd(&lacc[d >> 9], val);   // LDS atomic; graph id = dst / 512
    }
    __syncthreads();
    if (threadIdx.x < NB) atomicAdd(acc + threadIdx.x, lacc[threadIdx.x]);
}

// --- 5) finalize: f32 out — loss at out[0], y_pred at out[1..32] ------------
__global__ void d_final(const float* __restrict__ acc,
                        const float* __restrict__ y_data,
                        const float* __restrict__ b_wd,
                        const float* __restrict__ b_td,
                        const float* __restrict__ Wout,
                        const float* __restrict__ b_out,
                        float* __restrict__ out) {
    __shared__ float red[2];
    __shared__ float c0s;
    __shared__ float lsum[NB];
    int t = threadIdx.x;              // 128 threads
    float p = (b_wd[t] + b_td[t]) * Wout[t];
    #pragma unroll
    for (int off = 32; off; off >>= 1) p += __shfl_down(p, off);
    if ((t & 63) == 0) red[t >> 6] = p;
    __syncthreads();
    if (t == 0) c0s = red[0] + red[1] + b_out[0];
    __syncthreads();
    float c0 = c0s;
    if (t < NB) {
        float x = acc[t] * (1.0f / 512.0f) + c0;
        float y = y_data[t];
        lsum[t] = fmaxf(x, 0.f) - x * y + log1pf(expf(-fabsf(x)));
        out[1 + t] = 1.0f / (1.0f + expf(-x));
    }
    __syncthreads();
    if (t == 0) {
        float s = 0.f;
        #pragma unroll
        for (int i = 0; i < NB; ++i) s += lsum[i];
        out[0] = s / (float)NB;
    }
}

extern "C" void kernel_launch(void* const* d_in, const int* in_sizes, int n_in,
                              void* d_out, int out_size, void* d_ws, size_t ws_size,
                              hipStream_t stream) {
    const int* word_ids  = (const int*)d_in[0];
    const int* topic_ids = (const int*)d_in[1];
    const int* wd_src    = (const int*)d_in[2];
    const int* wd_dst    = (const int*)d_in[3];
    const int* td_src    = (const int*)d_in[4];
    const int* td_dst    = (const int*)d_in[5];
    const float* y_data  = (const float*)d_in[6];
    const float* wemb    = (const float*)d_in[7];
    const float* temb    = (const float*)d_in[8];
    const float* Wwd     = (const float*)d_in[9];
    const float* bwd     = (const float*)d_in[10];
    const float* Wtd     = (const float*)d_in[11];
    const float* btd     = (const float*)d_in[12];
    const float* Wout    = (const float*)d_in[13];
    const float* bout    = (const float*)d_in[14];
    float* out = (float*)d_out;          // f32 output (confirmed round 15)

    unsigned* wsbase = (unsigned*)d_ws;
    float* acc  = (float*)(wsbase + OFF_ACC);
    float* v    = (float*)(wsbase + 191168);
    float* u_wd = v + 2 * HD;
    float* u_td = u_wd + NWORD;

    // zero degrees + acc (proven-safe memset path)
    hipMemsetAsync(wsbase, 0, (size_t)NZWORDS * 4u, stream);

    d_deg<<<(EWD + ETD + 255) / 256, 256, 0, stream>>>(
        wd_src, wd_dst, td_src, td_dst, wsbase);
    d_v<<<1, HD, 0, stream>>>(Wwd, Wtd, Wout, v);
    d_u<<<(NWORD + NTOPIC + 3) / 4, 256, 0, stream>>>(wemb, temb, v, u_wd, u_td);
    d_edges<<<2048, 256, 0, stream>>>(wd_src, wd_dst, td_src, td_dst,
                                      word_ids, topic_ids, wsbase,
                                      u_wd, u_td, acc);
    d_final<<<1, HD, 0, stream>>>(acc, y_data, bwd, btd, Wout, bout, out);
}

// Round 17
// 116.972 us; speedup vs baseline: 1.7724x; 1.2983x over previous
//
#include <hip/hip_runtime.h>
#include <hip/hip_bf16.h>

#define NWN    100000
#define NTN    1600
#define NDOC   16384
#define EWD    1000000
#define ETD    200000
#define NWORD  15000
#define NTOPIC 50
#define HD     128
#define NB     32
#define NSLAB  32

// ---- fast-path ws layout (u32 words) ----
#define OFF_DEGW  0         // 2 replicas x 400000 (node i at i*4)
#define OFF_ACC   800000    // 32 (zeroed together with degw)
#define OFF_DOCS  800032    // 16384 dense packed (wd lo16 | td hi16)
#define OFF_DEGT  816416    // 1600 dense
#define OFF_V     818016    // 256 f32
#define OFF_UW    818272    // 15000 f32
#define OFF_UT    833272    // 64 f32
#define OFF_UNW   833336    // 100000 f32
#define OFF_UNT   933336    // 1600 f32
#define OFF_SLABA 934936    // 32 x 16384
#define OFF_SLABB 1459224   // 32 x 1600
#define WS_FAST_WORDS 1510424u

// ---- fallback (R16) layout ----
#define G_OFF_DOCS 100000
#define G_OFF_DEGT 165536
#define G_OFF_ACC  191136
#define G_NZWORDS  191168

// === fast path kernels ======================================================

// doc in-degree histogram: LDS-private, 32 slabs
__global__ void e_hdocs(const int* __restrict__ wd_dst, const int* __restrict__ td_dst,
                        unsigned* __restrict__ wsbase) {
    __shared__ unsigned h[NDOC];                     // 64 KB
    unsigned* slab = wsbase + OFF_SLABA;
    int tid = threadIdx.x;
    for (int k = tid; k < NDOC; k += 1024) h[k] = 0u;
    __syncthreads();
    const int total = EWD + ETD;
    for (int i = blockIdx.x * 1024 + tid; i < total; i += NSLAB * 1024) {
        if (i < EWD) atomicAdd(&h[wd_dst[i]], 1u);
        else         atomicAdd(&h[td_dst[i - EWD]], 65536u);
    }
    __syncthreads();
    for (int k = tid; k < NDOC; k += 1024)
        slab[blockIdx.x * NDOC + k] = h[k];
}

// topic out-degree histogram
__global__ void e_htop(const int* __restrict__ td_src, unsigned* __restrict__ wsbase) {
    __shared__ unsigned h[NTN];
    unsigned* slab = wsbase + OFF_SLABB;
    int tid = threadIdx.x;
    for (int k = tid; k < NTN; k += 1024) h[k] = 0u;
    __syncthreads();
    for (int i = blockIdx.x * 1024 + tid; i < ETD; i += NSLAB * 1024)
        atomicAdd(&h[td_src[i]], 1u);
    __syncthreads();
    for (int k = tid; k < NTN; k += 1024)
        slab[blockIdx.x * NTN + k] = h[k];
}

// word out-degrees: global atomics, stride 4, 2 replicas
__global__ void e_degw(const int* __restrict__ wd_src, unsigned* __restrict__ wsbase) {
    unsigned* base = wsbase + OFF_DEGW + (blockIdx.x & 1) * 400000;
    for (int i = blockIdx.x * blockDim.x + threadIdx.x; i < EWD;
         i += gridDim.x * blockDim.x)
        atomicAdd(base + wd_src[i] * 4, 1u);
}

// reduce slabs -> dense docs[] and deg_t[]
__global__ void e_red(unsigned* __restrict__ wsbase) {
    const unsigned* slabA = wsbase + OFF_SLABA;
    const unsigned* slabB = wsbase + OFF_SLABB;
    unsigned* docs = wsbase + OFF_DOCS;
    unsigned* degt = wsbase + OFF_DEGT;
    int t = blockIdx.x * blockDim.x + threadIdx.x;
    if (t < NDOC) {
        unsigned s = 0u;
        #pragma unroll
        for (int j = 0; j < NSLAB; ++j) s += slabA[j * NDOC + t];
        docs[t] = s;
    } else if (t < NDOC + NTN) {
        int k = t - NDOC;
        unsigned s = 0u;
        #pragma unroll
        for (int j = 0; j < NSLAB; ++j) s += slabB[j * NTN + k];
        degt[k] = s;
    }
}

// v = [W_wd @ W_out | W_td @ W_out]
__global__ void e_v(const float* __restrict__ Wwd, const float* __restrict__ Wtd,
                    const float* __restrict__ Wout, float* __restrict__ v) {
    __shared__ float wout[HD];
    int t = threadIdx.x;
    wout[t] = Wout[t];
    __syncthreads();
    float s1 = 0.f, s2 = 0.f;
    for (int j = 0; j < HD; ++j) {
        s1 += Wwd[t * HD + j] * wout[j];
        s2 += Wtd[t * HD + j] * wout[j];
    }
    v[t] = s1;
    v[t + HD] = s2;
}

// u[row] = emb_row . v (one wave per row)
__global__ void e_u(const float* __restrict__ wemb, const float* __restrict__ temb,
                    const float* __restrict__ v,
                    float* __restrict__ u_wd, float* __restrict__ u_td) {
    int wave = threadIdx.x >> 6;
    int lane = threadIdx.x & 63;
    int row  = blockIdx.x * (blockDim.x >> 6) + wave;
    const float* src; const float* vv; float* dst; int r;
    if (row < NWORD)               { src = wemb; vv = v;      dst = u_wd; r = row; }
    else if (row < NWORD + NTOPIC) { src = temb; vv = v + HD; dst = u_td; r = row - NWORD; }
    else return;
    float s = src[r * HD + lane]      * vv[lane]
            + src[r * HD + lane + 64] * vv[lane + 64];
    #pragma unroll
    for (int off = 32; off; off >>= 1) s += __shfl_down(s, off);
    if (lane == 0) dst[r] = s;
}

// per-node scalars with outdeg norm folded (merges deg_w replicas)
__global__ void e_un(const int* __restrict__ wids, const int* __restrict__ tids,
                     const unsigned* __restrict__ wsbase,
                     const float* __restrict__ u_wd, const float* __restrict__ u_td,
                     float* __restrict__ un_w, float* __restrict__ un_t) {
    const unsigned* dw = wsbase + OFF_DEGW;
    const unsigned* dt = wsbase + OFF_DEGT;
    int i = blockIdx.x * blockDim.x + threadIdx.x;
    if (i < NWN) {
        unsigned d = dw[i * 4] + dw[400000 + i * 4];
        un_w[i] = u_wd[wids[i]] * rsqrtf((float)(d > 1u ? d : 1u));
    } else if (i < NWN + NTN) {
        int j = i - NWN;
        unsigned d = dt[j];
        un_t[j] = u_td[tids[j]] * rsqrtf((float)(d > 1u ? d : 1u));
    }
}

// edge scalar accumulation into 32 graph slots
__global__ void e_edges(const int* __restrict__ wd_src, const int* __restrict__ wd_dst,
                        const int* __restrict__ td_src, const int* __restrict__ td_dst,
                        const unsigned* __restrict__ wsbase,
                        const float* __restrict__ un_w, const float* __restrict__ un_t,
                        float* __restrict__ acc) {
    const unsigned* docs = wsbase + OFF_DOCS;
    __shared__ float lacc[NB];
    if (threadIdx.x < NB) lacc[threadIdx.x] = 0.f;
    __syncthreads();
    const int total = EWD + ETD;
    for (int i = blockIdx.x * blockDim.x + threadIdx.x; i < total;
         i += gridDim.x * blockDim.x) {
        int d; float val;
        if (i < EWD) {
            int s = wd_src[i]; d = wd_dst[i];
            unsigned b = docs[d] & 0xFFFFu;
            val = un_w[s] * rsqrtf((float)(b > 1u ? b : 1u));
        } else {
            int e = i - EWD;
            int s = td_src[e]; d = td_dst[e];
            unsigned b = docs[d] >> 16;
            val = un_t[s] * rsqrtf((float)(b > 1u ? b : 1u));
        }
        atomicAdd(&lacc[d >> 9], val);
    }
    __syncthreads();
    if (threadIdx.x < NB) atomicAdd(acc + threadIdx.x, lacc[threadIdx.x]);
}

// finalize (f32 out): loss at out[0], y_pred at out[1..32]
__global__ void e_final(const float* __restrict__ acc, const float* __restrict__ y_data,
                        const float* __restrict__ b_wd, const float* __restrict__ b_td,
                        const float* __restrict__ Wout, const float* __restrict__ b_out,
                        float* __restrict__ out) {
    __shared__ float red[2];
    __shared__ float c0s;
    __shared__ float lsum[NB];
    int t = threadIdx.x;
    float p = (b_wd[t] + b_td[t]) * Wout[t];
    #pragma unroll
    for (int off = 32; off; off >>= 1) p += __shfl_down(p, off);
    if ((t & 63) == 0) red[t >> 6] = p;
    __syncthreads();
    if (t == 0) c0s = red[0] + red[1] + b_out[0];
    __syncthreads();
    float c0 = c0s;
    if (t < NB) {
        float x = acc[t] * (1.0f / 512.0f) + c0;
        float y = y_data[t];
        lsum[t] = fmaxf(x, 0.f) - x * y + log1pf(expf(-fabsf(x)));
        out[1 + t] = 1.0f / (1.0f + expf(-x));
    }
    __syncthreads();
    if (t == 0) {
        float s = 0.f;
        #pragma unroll
        for (int i = 0; i < NB; ++i) s += lsum[i];
        out[0] = s / (float)NB;
    }
}

// === fallback (R16-proven) kernels =========================================

__global__ void g_deg(const int* __restrict__ wd_src, const int* __restrict__ wd_dst,
                      const int* __restrict__ td_src, const int* __restrict__ td_dst,
                      unsigned* __restrict__ wsbase) {
    unsigned* deg_w = wsbase;
    unsigned* docs  = wsbase + G_OFF_DOCS;
    unsigned* deg_t = wsbase + G_OFF_DEGT;
    int i = blockIdx.x * blockDim.x + threadIdx.x;
    if (i < EWD) {
        atomicAdd(deg_w + wd_src[i], 1u);
        atomicAdd(docs + wd_dst[i] * 4, 1u);
    } else if (i < EWD + ETD) {
        int e = i - EWD;
        atomicAdd(deg_t + td_src[e] * 16, 1u);
        atomicAdd(docs + td_dst[e] * 4, 65536u);
    }
}

__global__ void g_edges(const int* __restrict__ wd_src, const int* __restrict__ wd_dst,
                        const int* __restrict__ td_src, const int* __restrict__ td_dst,
                        const int* __restrict__ wids, const int* __restrict__ tids,
                        const unsigned* __restrict__ wsbase,
                        const float* __restrict__ u_wd, const float* __restrict__ u_td,
                        float* __restrict__ acc) {
    const unsigned* deg_w = wsbase;
    const unsigned* docs  = wsbase + G_OFF_DOCS;
    const unsigned* deg_t = wsbase + G_OFF_DEGT;
    __shared__ float lacc[NB];
    if (threadIdx.x < NB) lacc[threadIdx.x] = 0.f;
    __syncthreads();
    const int total = EWD + ETD;
    for (int i = blockIdx.x * blockDim.x + threadIdx.x; i < total;
         i += gridDim.x * blockDim.x) {
        int d; float val;
        if (i < EWD) {
            int s = wd_src[i]; d = wd_dst[i];
            unsigned a = deg_w[s];
            unsigned b = docs[d * 4] & 0xFFFFu;
            val = u_wd[wids[s]] * rsqrtf((float)(a > 1u ? a : 1u))
                                * rsqrtf((float)(b > 1u ? b : 1u));
        } else {
            int e = i - EWD;
            int s = td_src[e]; d = td_dst[e];
            unsigned a = deg_t[s * 16];
            unsigned b = docs[d * 4] >> 16;
            val = u_td[tids[s]] * rsqrtf((float)(a > 1u ? a : 1u))
                               * rsqrtf((float)(b > 1u ? b : 1u));
        }
        atomicAdd(&lacc[d >> 9], val);
    }
    __syncthreads();
    if (threadIdx.x < NB) atomicAdd(acc + threadIdx.x, lacc[threadIdx.x]);
}

extern "C" void kernel_launch(void* const* d_in, const int* in_sizes, int n_in,
                              void* d_out, int out_size, void* d_ws, size_t ws_size,
                              hipStream_t stream) {
    const int* word_ids  = (const int*)d_in[0];
    const int* topic_ids = (const int*)d_in[1];
    const int* wd_src    = (const int*)d_in[2];
    const int* wd_dst    = (const int*)d_in[3];
    const int* td_src    = (const int*)d_in[4];
    const int* td_dst    = (const int*)d_in[5];
    const float* y_data  = (const float*)d_in[6];
    const float* wemb    = (const float*)d_in[7];
    const float* temb    = (const float*)d_in[8];
    const float* Wwd     = (const float*)d_in[9];
    const float* bwd     = (const float*)d_in[10];
    const float* Wtd     = (const float*)d_in[11];
    const float* btd     = (const float*)d_in[12];
    const float* Wout    = (const float*)d_in[13];
    const float* bout    = (const float*)d_in[14];
    float* out = (float*)d_out;
    unsigned* wsbase = (unsigned*)d_ws;

    if (ws_size >= (size_t)WS_FAST_WORDS * 4u) {
        // ---- fast path: LDS histograms + replicated strided deg_w ----
        float* acc  = (float*)(wsbase + OFF_ACC);
        float* v    = (float*)(wsbase + OFF_V);
        float* u_wd = (float*)(wsbase + OFF_UW);
        float* u_td = (float*)(wsbase + OFF_UT);
        float* un_w = (float*)(wsbase + OFF_UNW);
        float* un_t = (float*)(wsbase + OFF_UNT);

        hipMemsetAsync(wsbase, 0, (size_t)(800000 + NB) * 4u, stream);  // degw + acc
        e_v<<<1, HD, 0, stream>>>(Wwd, Wtd, Wout, v);
        e_u<<<(NWORD + NTOPIC + 3) / 4, 256, 0, stream>>>(wemb, temb, v, u_wd, u_td);
        e_hdocs<<<NSLAB, 1024, 0, stream>>>(wd_dst, td_dst, wsbase);
        e_htop<<<NSLAB, 1024, 0, stream>>>(td_src, wsbase);
        e_degw<<<2048, 256, 0, stream>>>(wd_src, wsbase);
        e_red<<<(NDOC + NTN + 255) / 256, 256, 0, stream>>>(wsbase);
        e_un<<<(NWN + NTN + 255) / 256, 256, 0, stream>>>(
            word_ids, topic_ids, wsbase, u_wd, u_td, un_w, un_t);
        e_edges<<<2048, 256, 0, stream>>>(wd_src, wd_dst, td_src, td_dst,
                                          wsbase, un_w, un_t, acc);
        e_final<<<1, HD, 0, stream>>>(acc, y_data, bwd, btd, Wout, bout, out);
    } else {
        // ---- fallback: proven R16 path (826 KB) ----
        float* acc  = (float*)(wsbase + G_OFF_ACC);
        float* v    = (float*)(wsbase + G_NZWORDS);
        float* u_wd = v + 2 * HD;
        float* u_td = u_wd + NWORD;

        hipMemsetAsync(wsbase, 0, (size_t)G_NZWORDS * 4u, stream);
        g_deg<<<(EWD + ETD + 255) / 256, 256, 0, stream>>>(
            wd_src, wd_dst, td_src, td_dst, wsbase);
        e_v<<<1, HD, 0, stream>>>(Wwd, Wtd, Wout, v);
        e_u<<<(NWORD + NTOPIC + 3) / 4, 256, 0, stream>>>(wemb, temb, v, u_wd, u_td);
        g_edges<<<2048, 256, 0, stream>>>(wd_src, wd_dst, td_src, td_dst,
                                          word_ids, topic_ids, wsbase,
                                          u_wd, u_td, acc);
        e_final<<<1, HD, 0, stream>>>(acc, y_data, bwd, btd, Wout, bout, out);
    }
}

// Round 18
// 65.632 us; speedup vs baseline: 3.1589x; 1.7822x over previous
//
#include <hip/hip_runtime.h>
#include <hip/hip_bf16.h>

#define NWN    100000
#define NTN    1600
#define NDOC   16384
#define EWD    1000000
#define ETD    200000
#define NWORD  15000
#define NTOPIC 50
#define HD     128
#define NB     32
#define NSW    32       // word-hist slabs (u8-packed)
#define NSD    16       // doc-hist slabs (u16-packed pairs)
#define NST    16       // topic-hist slabs
#define WRDW   25000    // u32 words holding 100000 u8 counters

// ---- ws layout (u32 words), total 1221088 words = 4.88 MB ----
#define O_SLABW 0         // NSW*WRDW      = 800000
#define O_SLABD 800000    // NSD*NDOC      = 262144
#define O_SLABT 1062144   // NST*NTN       = 25600
#define O_DOCS  1087744   // 16384 packed (wd lo16 | td hi16)
#define O_UNW   1104128   // 100000 f32
#define O_UNT   1204128   // 1600 f32
#define O_V     1205728   // 256 f32
#define O_UW    1205984   // 15000 f32
#define O_UT    1220984   // 64 f32
#define O_ACC   1221048   // 32 f32
#define O_CNT   1221080   // 8 u32

// --- 1) all degree histograms, LDS-private, zero global atomics -------------
__global__ void __launch_bounds__(1024) f_hist(const int* __restrict__ wd_src,
                                               const int* __restrict__ wd_dst,
                                               const int* __restrict__ td_src,
                                               const int* __restrict__ td_dst,
                                               unsigned* __restrict__ ws) {
    __shared__ unsigned h[WRDW];          // 100 KB, used partially by roles B/C
    int tid = threadIdx.x;
    int b   = blockIdx.x;
    if (b < NSW) {
        // word out-degrees: u8 counters packed 4-per-word
        for (int k = tid; k < WRDW; k += 1024) h[k] = 0u;
        __syncthreads();
        const int4* p = (const int4*)wd_src;
        for (int i = b * 1024 + tid; i < EWD / 4; i += NSW * 1024) {
            int4 s = p[i];
            atomicAdd(&h[((unsigned)s.x) >> 2], 1u << (8 * (s.x & 3)));
            atomicAdd(&h[((unsigned)s.y) >> 2], 1u << (8 * (s.y & 3)));
            atomicAdd(&h[((unsigned)s.z) >> 2], 1u << (8 * (s.z & 3)));
            atomicAdd(&h[((unsigned)s.w) >> 2], 1u << (8 * (s.w & 3)));
        }
        __syncthreads();
        unsigned* slab = ws + O_SLABW + b * WRDW;
        for (int k = tid; k < WRDW; k += 1024) slab[k] = h[k];
    } else if (b < NSW + NSD) {
        // doc in-degrees: wd in lo16, td in hi16
        int sb = b - NSW;
        for (int k = tid; k < NDOC; k += 1024) h[k] = 0u;
        __syncthreads();
        const int4* p = (const int4*)wd_dst;
        for (int i = sb * 1024 + tid; i < EWD / 4; i += NSD * 1024) {
            int4 d = p[i];
            atomicAdd(&h[d.x], 1u); atomicAdd(&h[d.y], 1u);
            atomicAdd(&h[d.z], 1u); atomicAdd(&h[d.w], 1u);
        }
        const int4* q = (const int4*)td_dst;
        for (int i = sb * 1024 + tid; i < ETD / 4; i += NSD * 1024) {
            int4 d = q[i];
            atomicAdd(&h[d.x], 65536u); atomicAdd(&h[d.y], 65536u);
            atomicAdd(&h[d.z], 65536u); atomicAdd(&h[d.w], 65536u);
        }
        __syncthreads();
        unsigned* slab = ws + O_SLABD + sb * NDOC;
        for (int k = tid; k < NDOC; k += 1024) slab[k] = h[k];
    } else {
        // topic out-degrees
        int sb = b - NSW - NSD;
        for (int k = tid; k < NTN; k += 1024) h[k] = 0u;
        __syncthreads();
        const int4* p = (const int4*)td_src;
        for (int i = sb * 1024 + tid; i < ETD / 4; i += NST * 1024) {
            int4 s = p[i];
            atomicAdd(&h[s.x], 1u); atomicAdd(&h[s.y], 1u);
            atomicAdd(&h[s.z], 1u); atomicAdd(&h[s.w], 1u);
        }
        __syncthreads();
        unsigned* slab = ws + O_SLABT + sb * NTN;
        for (int k = tid; k < NTN; k += 1024) slab[k] = h[k];
    }
}

// --- 2) v = [W_wd @ W_out | W_td @ W_out]; also zero acc + done-counter -----
__global__ void f_v(const float* __restrict__ Wwd, const float* __restrict__ Wtd,
                    const float* __restrict__ Wout, unsigned* __restrict__ ws) {
    __shared__ float wout[HD];
    int t = threadIdx.x;              // 128 threads
    float* v = (float*)(ws + O_V);
    wout[t] = Wout[t];
    __syncthreads();
    float s1 = 0.f, s2 = 0.f;
    for (int j = 0; j < HD; ++j) {
        s1 += Wwd[t * HD + j] * wout[j];
        s2 += Wtd[t * HD + j] * wout[j];
    }
    v[t]      = s1;
    v[t + HD] = s2;
    if (t < NB) ((float*)(ws + O_ACC))[t] = 0.f;
    if (t == NB) ws[O_CNT] = 0u;
}

// --- 3) u[row] = emb_row . v  (one wave per row) -----------------------------
__global__ void f_u(const float* __restrict__ wemb, const float* __restrict__ temb,
                    unsigned* __restrict__ ws) {
    const float* v = (const float*)(ws + O_V);
    int wave = threadIdx.x >> 6;
    int lane = threadIdx.x & 63;
    int row  = blockIdx.x * (blockDim.x >> 6) + wave;
    const float* src; const float* vv; float* dst; int r;
    if (row < NWORD) {
        src = wemb; vv = v; dst = (float*)(ws + O_UW); r = row;
    } else if (row < NWORD + NTOPIC) {
        src = temb; vv = v + HD; dst = (float*)(ws + O_UT); r = row - NWORD;
    } else return;
    float s = src[r * HD + lane]      * vv[lane]
            + src[r * HD + lane + 64] * vv[lane + 64];
    #pragma unroll
    for (int off = 32; off; off >>= 1) s += __shfl_down(s, off);
    if (lane == 0) dst[r] = s;
}

// --- 4) reduce slabs + fold outdeg norm + embedding gather ------------------
__global__ void f_un(const int* __restrict__ wids, const int* __restrict__ tids,
                     unsigned* __restrict__ ws) {
    const unsigned* slabW = ws + O_SLABW;
    const unsigned* slabD = ws + O_SLABD;
    const unsigned* slabT = ws + O_SLABT;
    unsigned* docs = ws + O_DOCS;
    const float* u_wd = (const float*)(ws + O_UW);
    const float* u_td = (const float*)(ws + O_UT);
    float* un_w = (float*)(ws + O_UNW);
    float* un_t = (float*)(ws + O_UNT);
    int t = blockIdx.x * blockDim.x + threadIdx.x;
    if (t < NWN) {
        int w = t >> 2, sh = 8 * (t & 3);
        unsigned d = 0u;
        #pragma unroll
        for (int j = 0; j < NSW; ++j) d += (slabW[j * WRDW + w] >> sh) & 0xFFu;
        un_w[t] = u_wd[wids[t]] * rsqrtf((float)(d > 1u ? d : 1u));
    } else if (t < NWN + NDOC) {
        int k = t - NWN;
        unsigned s = 0u;
        #pragma unroll
        for (int j = 0; j < NSD; ++j) s += slabD[j * NDOC + k];
        docs[k] = s;    // lo16/hi16 sums can't cross-carry (max ~110/~40)
    } else if (t < NWN + NDOC + NTN) {
        int k = t - NWN - NDOC;
        unsigned d = 0u;
        #pragma unroll
        for (int j = 0; j < NST; ++j) d += slabT[j * NTN + k];
        un_t[k] = u_td[tids[k]] * rsqrtf((float)(d > 1u ? d : 1u));
    }
}

// --- 5) edges + last-block finalize -----------------------------------------
__global__ void __launch_bounds__(256) f_edges(const int* __restrict__ wd_src,
                                               const int* __restrict__ wd_dst,
                                               const int* __restrict__ td_src,
                                               const int* __restrict__ td_dst,
                                               const float* __restrict__ y_data,
                                               const float* __restrict__ b_wd,
                                               const float* __restrict__ b_td,
                                               const float* __restrict__ Wout,
                                               const float* __restrict__ b_out,
                                               unsigned* __restrict__ ws,
                                               float* __restrict__ out) {
    const unsigned* docs = ws + O_DOCS;
    const float* un_w = (const float*)(ws + O_UNW);
    const float* un_t = (const float*)(ws + O_UNT);
    float* acc = (float*)(ws + O_ACC);
    __shared__ float lacc[NB];
    __shared__ unsigned lastflag;
    int tid = threadIdx.x;
    if (tid < NB) lacc[tid] = 0.f;
    __syncthreads();
    int nthr = gridDim.x * blockDim.x;
    const int4* ps = (const int4*)wd_src;
    const int4* pd = (const int4*)wd_dst;
    for (int i = blockIdx.x * blockDim.x + tid; i < EWD / 4; i += nthr) {
        int4 s = ps[i]; int4 d = pd[i];
        unsigned b;
        b = docs[d.x] & 0xFFFFu;
        atomicAdd(&lacc[d.x >> 9], un_w[s.x] * rsqrtf((float)(b > 1u ? b : 1u)));
        b = docs[d.y] & 0xFFFFu;
        atomicAdd(&lacc[d.y >> 9], un_w[s.y] * rsqrtf((float)(b > 1u ? b : 1u)));
        b = docs[d.z] & 0xFFFFu;
        atomicAdd(&lacc[d.z >> 9], un_w[s.z] * rsqrtf((float)(b > 1u ? b : 1u)));
        b = docs[d.w] & 0xFFFFu;
        atomicAdd(&lacc[d.w >> 9], un_w[s.w] * rsqrtf((float)(b > 1u ? b : 1u)));
    }
    const int4* qs = (const int4*)td_src;
    const int4* qd = (const int4*)td_dst;
    for (int i = blockIdx.x * blockDim.x + tid; i < ETD / 4; i += nthr) {
        int4 s = qs[i]; int4 d = qd[i];
        unsigned b;
        b = docs[d.x] >> 16;
        atomicAdd(&lacc[d.x >> 9], un_t[s.x] * rsqrtf((float)(b > 1u ? b : 1u)));
        b = docs[d.y] >> 16;
        atomicAdd(&lacc[d.y >> 9], un_t[s.y] * rsqrtf((float)(b > 1u ? b : 1u)));
        b = docs[d.z] >> 16;
        atomicAdd(&lacc[d.z >> 9], un_t[s.z] * rsqrtf((float)(b > 1u ? b : 1u)));
        b = docs[d.w] >> 16;
        atomicAdd(&lacc[d.w >> 9], un_t[s.w] * rsqrtf((float)(b > 1u ? b : 1u)));
    }
    __syncthreads();
    if (tid < NB) atomicAdd(&acc[tid], lacc[tid]);
    if (tid == 0) {
        __threadfence();
        unsigned prev = atomicAdd(&ws[O_CNT], 1u);
        lastflag = (prev == (unsigned)gridDim.x - 1u) ? 1u : 0u;
    }
    __syncthreads();
    // last block, wave 0 only: finalize (shuffle-only, no __syncthreads)
    if (lastflag && tid < 64) {
        // c0 = (b_wd + b_td) . W_out + b_out  (each lane handles 2 elements)
        float p = (b_wd[tid] + b_td[tid]) * Wout[tid]
                + (b_wd[tid + 64] + b_td[tid + 64]) * Wout[tid + 64];
        #pragma unroll
        for (int off = 32; off; off >>= 1) p += __shfl_down(p, off);
        float c0 = __shfl(p, 0) + b_out[0];
        float l = 0.f;
        if (tid < NB) {
            float a = atomicAdd(&acc[tid], 0.0f);   // coherent read
            float x = a * (1.0f / 512.0f) + c0;
            float y = y_data[tid];
            l = fmaxf(x, 0.f) - x * y + log1pf(expf(-fabsf(x)));
            out[1 + tid] = 1.0f / (1.0f + expf(-x));
        }
        #pragma unroll
        for (int off = 16; off; off >>= 1) l += __shfl_down(l, off);
        if (tid == 0) out[0] = l * (1.0f / (float)NB);
    }
}

extern "C" void kernel_launch(void* const* d_in, const int* in_sizes, int n_in,
                              void* d_out, int out_size, void* d_ws, size_t ws_size,
                              hipStream_t stream) {
    const int* word_ids  = (const int*)d_in[0];
    const int* topic_ids = (const int*)d_in[1];
    const int* wd_src    = (const int*)d_in[2];
    const int* wd_dst    = (const int*)d_in[3];
    const int* td_src    = (const int*)d_in[4];
    const int* td_dst    = (const int*)d_in[5];
    const float* y_data  = (const float*)d_in[6];
    const float* wemb    = (const float*)d_in[7];
    const float* temb    = (const float*)d_in[8];
    const float* Wwd     = (const float*)d_in[9];
    const float* bwd     = (const float*)d_in[10];
    const float* Wtd     = (const float*)d_in[11];
    const float* btd     = (const float*)d_in[12];
    const float* Wout    = (const float*)d_in[13];
    const float* bout    = (const float*)d_in[14];
    float* out = (float*)d_out;
    unsigned* ws = (unsigned*)d_ws;

    f_v<<<1, HD, 0, stream>>>(Wwd, Wtd, Wout, ws);
    f_u<<<(NWORD + NTOPIC + 3) / 4, 256, 0, stream>>>(wemb, temb, ws);
    f_hist<<<NSW + NSD + NST, 1024, 0, stream>>>(wd_src, wd_dst, td_src, td_dst, ws);
    f_un<<<(NWN + NDOC + NTN + 255) / 256, 256, 0, stream>>>(word_ids, topic_ids, ws);
    f_edges<<<1024, 256, 0, stream>>>(wd_src, wd_dst, td_src, td_dst,
                                      y_data, bwd, btd, Wout, bout, ws, out);
}

// Round 19
// 64.517 us; speedup vs baseline: 3.2135x; 1.0173x over previous
//
#include <hip/hip_runtime.h>
#include <hip/hip_bf16.h>

#define NWN    100000
#define NTN    1600
#define NDOC   16384
#define EWD    1000000
#define ETD    200000
#define NWORD  15000
#define NTOPIC 50
#define HD     128
#define NB     32
#define NSW    32       // word-hist slabs (u8-packed)
#define NSD    16       // doc-hist slabs (u16-packed pairs)
#define NST    16       // topic-hist slabs
#define WRDW   25000    // u32 words holding 100000 u8 counters
#define NBLK_E 1172     // edge blocks: 300000 int4 units / 256 (= 4*293)

// ---- ws layout (u32 words), total 1258552 words = 5.03 MB ----
#define O_SLABW 0         // NSW*WRDW = 800000
#define O_SLABD 800000    // NSD*NDOC = 262144
#define O_SLABT 1062144   // NST*NTN  = 25600
#define O_DOCS  1087744   // 16384 packed (wd lo16 | td hi16)
#define O_UNW   1104128   // 100000 f32
#define O_UNT   1204128   // 1600 f32
#define O_V     1205728   // 256 f32
#define O_UW    1205984   // 15000 f32
#define O_UT    1220984   // 64 f32
#define O_PART  1221048   // NBLK_E*NB = 37504 f32

// --- 1) all degree histograms, LDS-private, zero global atomics -------------
__global__ void __launch_bounds__(1024) f_hist(const int* __restrict__ wd_src,
                                               const int* __restrict__ wd_dst,
                                               const int* __restrict__ td_src,
                                               const int* __restrict__ td_dst,
                                               unsigned* __restrict__ ws) {
    __shared__ unsigned h[WRDW];          // 100 KB max (word role)
    int tid = threadIdx.x;
    int b   = blockIdx.x;
    if (b < NSW) {
        for (int k = tid; k < WRDW; k += 1024) h[k] = 0u;
        __syncthreads();
        const int4* p = (const int4*)wd_src;
        for (int i = b * 1024 + tid; i < EWD / 4; i += NSW * 1024) {
            int4 s = p[i];
            atomicAdd(&h[((unsigned)s.x) >> 2], 1u << (8 * (s.x & 3)));
            atomicAdd(&h[((unsigned)s.y) >> 2], 1u << (8 * (s.y & 3)));
            atomicAdd(&h[((unsigned)s.z) >> 2], 1u << (8 * (s.z & 3)));
            atomicAdd(&h[((unsigned)s.w) >> 2], 1u << (8 * (s.w & 3)));
        }
        __syncthreads();
        unsigned* slab = ws + O_SLABW + b * WRDW;
        for (int k = tid; k < WRDW; k += 1024) slab[k] = h[k];
    } else if (b < NSW + NSD) {
        int sb = b - NSW;
        for (int k = tid; k < NDOC; k += 1024) h[k] = 0u;
        __syncthreads();
        const int4* p = (const int4*)wd_dst;
        for (int i = sb * 1024 + tid; i < EWD / 4; i += NSD * 1024) {
            int4 d = p[i];
            atomicAdd(&h[d.x], 1u); atomicAdd(&h[d.y], 1u);
            atomicAdd(&h[d.z], 1u); atomicAdd(&h[d.w], 1u);
        }
        const int4* q = (const int4*)td_dst;
        for (int i = sb * 1024 + tid; i < ETD / 4; i += NSD * 1024) {
            int4 d = q[i];
            atomicAdd(&h[d.x], 65536u); atomicAdd(&h[d.y], 65536u);
            atomicAdd(&h[d.z], 65536u); atomicAdd(&h[d.w], 65536u);
        }
        __syncthreads();
        unsigned* slab = ws + O_SLABD + sb * NDOC;
        for (int k = tid; k < NDOC; k += 1024) slab[k] = h[k];
    } else {
        int sb = b - NSW - NSD;
        for (int k = tid; k < NTN; k += 1024) h[k] = 0u;
        __syncthreads();
        const int4* p = (const int4*)td_src;
        for (int i = sb * 1024 + tid; i < ETD / 4; i += NST * 1024) {
            int4 s = p[i];
            atomicAdd(&h[s.x], 1u); atomicAdd(&h[s.y], 1u);
            atomicAdd(&h[s.z], 1u); atomicAdd(&h[s.w], 1u);
        }
        __syncthreads();
        unsigned* slab = ws + O_SLABT + sb * NTN;
        for (int k = tid; k < NTN; k += 1024) slab[k] = h[k];
    }
}

// --- 2) v = [W_wd @ W_out | W_td @ W_out] -----------------------------------
__global__ void f_v(const float* __restrict__ Wwd, const float* __restrict__ Wtd,
                    const float* __restrict__ Wout, unsigned* __restrict__ ws) {
    __shared__ float wout[HD];
    int t = threadIdx.x;              // 128 threads
    float* v = (float*)(ws + O_V);
    wout[t] = Wout[t];
    __syncthreads();
    float s1 = 0.f, s2 = 0.f;
    for (int j = 0; j < HD; ++j) {
        s1 += Wwd[t * HD + j] * wout[j];
        s2 += Wtd[t * HD + j] * wout[j];
    }
    v[t]      = s1;
    v[t + HD] = s2;
}

// --- 3) u[row] = emb_row . v  (one wave per row) -----------------------------
__global__ void f_u(const float* __restrict__ wemb, const float* __restrict__ temb,
                    unsigned* __restrict__ ws) {
    const float* v = (const float*)(ws + O_V);
    int wave = threadIdx.x >> 6;
    int lane = threadIdx.x & 63;
    int row  = blockIdx.x * (blockDim.x >> 6) + wave;
    const float* src; const float* vv; float* dst; int r;
    if (row < NWORD) {
        src = wemb; vv = v; dst = (float*)(ws + O_UW); r = row;
    } else if (row < NWORD + NTOPIC) {
        src = temb; vv = v + HD; dst = (float*)(ws + O_UT); r = row - NWORD;
    } else return;
    float s = src[r * HD + lane]      * vv[lane]
            + src[r * HD + lane + 64] * vv[lane + 64];
    #pragma unroll
    for (int off = 32; off; off >>= 1) s += __shfl_down(s, off);
    if (lane == 0) dst[r] = s;
}

// --- 4) reduce slabs + fold outdeg norm + embedding gather ------------------
__global__ void f_un(const int* __restrict__ wids, const int* __restrict__ tids,
                     unsigned* __restrict__ ws) {
    const unsigned* slabW = ws + O_SLABW;
    const unsigned* slabD = ws + O_SLABD;
    const unsigned* slabT = ws + O_SLABT;
    unsigned* docs = ws + O_DOCS;
    const float* u_wd = (const float*)(ws + O_UW);
    const float* u_td = (const float*)(ws + O_UT);
    float* un_w = (float*)(ws + O_UNW);
    float* un_t = (float*)(ws + O_UNT);
    int t = blockIdx.x * blockDim.x + threadIdx.x;
    if (t < NWN) {
        int w = t >> 2, sh = 8 * (t & 3);
        unsigned d = 0u;
        #pragma unroll
        for (int j = 0; j < NSW; ++j) d += (slabW[j * WRDW + w] >> sh) & 0xFFu;
        un_w[t] = u_wd[wids[t]] * rsqrtf((float)(d > 1u ? d : 1u));
    } else if (t < NWN + NDOC) {
        int k = t - NWN;
        unsigned s = 0u;
        #pragma unroll
        for (int j = 0; j < NSD; ++j) s += slabD[j * NDOC + k];
        docs[k] = s;    // lo16/hi16 sums can't cross-carry
    } else if (t < NWN + NDOC + NTN) {
        int k = t - NWN - NDOC;
        unsigned d = 0u;
        #pragma unroll
        for (int j = 0; j < NST; ++j) d += slabT[j * NTN + k];
        un_t[k] = u_td[tids[k]] * rsqrtf((float)(d > 1u ? d : 1u));
    }
}

// --- 5) edges: one int4 per thread, LDS acc, plain per-block partial store --
__global__ void __launch_bounds__(256) f_edges(const int* __restrict__ wd_src,
                                               const int* __restrict__ wd_dst,
                                               const int* __restrict__ td_src,
                                               const int* __restrict__ td_dst,
                                               unsigned* __restrict__ ws) {
    const unsigned* docs = ws + O_DOCS;
    const float* un_w = (const float*)(ws + O_UNW);
    const float* un_t = (const float*)(ws + O_UNT);
    float* part = (float*)(ws + O_PART);
    __shared__ float lacc[NB];
    int tid = threadIdx.x;
    if (tid < NB) lacc[tid] = 0.f;
    __syncthreads();
    int u = blockIdx.x * 256 + tid;
    if (u < EWD / 4) {
        int4 s = ((const int4*)wd_src)[u];
        int4 d = ((const int4*)wd_dst)[u];
        unsigned b;
        b = docs[d.x] & 0xFFFFu;
        atomicAdd(&lacc[d.x >> 9], un_w[s.x] * rsqrtf((float)(b > 1u ? b : 1u)));
        b = docs[d.y] & 0xFFFFu;
        atomicAdd(&lacc[d.y >> 9], un_w[s.y] * rsqrtf((float)(b > 1u ? b : 1u)));
        b = docs[d.z] & 0xFFFFu;
        atomicAdd(&lacc[d.z >> 9], un_w[s.z] * rsqrtf((float)(b > 1u ? b : 1u)));
        b = docs[d.w] & 0xFFFFu;
        atomicAdd(&lacc[d.w >> 9], un_w[s.w] * rsqrtf((float)(b > 1u ? b : 1u)));
    } else if (u < EWD / 4 + ETD / 4) {
        int e = u - EWD / 4;
        int4 s = ((const int4*)td_src)[e];
        int4 d = ((const int4*)td_dst)[e];
        unsigned b;
        b = docs[d.x] >> 16;
        atomicAdd(&lacc[d.x >> 9], un_t[s.x] * rsqrtf((float)(b > 1u ? b : 1u)));
        b = docs[d.y] >> 16;
        atomicAdd(&lacc[d.y >> 9], un_t[s.y] * rsqrtf((float)(b > 1u ? b : 1u)));
        b = docs[d.z] >> 16;
        atomicAdd(&lacc[d.z >> 9], un_t[s.z] * rsqrtf((float)(b > 1u ? b : 1u)));
        b = docs[d.w] >> 16;
        atomicAdd(&lacc[d.w >> 9], un_t[s.w] * rsqrtf((float)(b > 1u ? b : 1u)));
    }
    __syncthreads();
    if (tid < NB) part[blockIdx.x * NB + tid] = lacc[tid];
}

// --- 6) finalize: reduce 1172x32 partials, c0, BCE loss, sigmoid ------------
__global__ void f_fin(const float* __restrict__ y_data,
                      const float* __restrict__ b_wd,
                      const float* __restrict__ b_td,
                      const float* __restrict__ Wout,
                      const float* __restrict__ b_out,
                      unsigned* __restrict__ ws,
                      float* __restrict__ out) {
    const float* part = (const float*)(ws + O_PART);
    __shared__ float quarter[4][NB];
    __shared__ float red[2];
    __shared__ float c0s;
    __shared__ float lsum[NB];
    int t = threadIdx.x;              // 128 threads
    int g = t & 31, q = t >> 5;
    float s = 0.f;
    for (int j = q * (NBLK_E / 4); j < (q + 1) * (NBLK_E / 4); ++j)
        s += part[j * NB + g];
    quarter[q][g] = s;
    float p = (b_wd[t] + b_td[t]) * Wout[t];
    #pragma unroll
    for (int off = 32; off; off >>= 1) p += __shfl_down(p, off);
    if ((t & 63) == 0) red[t >> 6] = p;
    __syncthreads();
    if (t == 0) c0s = red[0] + red[1] + b_out[0];
    __syncthreads();
    if (t < NB) {
        float acc = quarter[0][t] + quarter[1][t] + quarter[2][t] + quarter[3][t];
        float x = acc * (1.0f / 512.0f) + c0s;
        float y = y_data[t];
        lsum[t] = fmaxf(x, 0.f) - x * y + log1pf(expf(-fabsf(x)));
        out[1 + t] = 1.0f / (1.0f + expf(-x));
    }
    __syncthreads();
    if (t == 0) {
        float ss = 0.f;
        #pragma unroll
        for (int i = 0; i < NB; ++i) ss += lsum[i];
        out[0] = ss / (float)NB;
    }
}

extern "C" void kernel_launch(void* const* d_in, const int* in_sizes, int n_in,
                              void* d_out, int out_size, void* d_ws, size_t ws_size,
                              hipStream_t stream) {
    const int* word_ids  = (const int*)d_in[0];
    const int* topic_ids = (const int*)d_in[1];
    const int* wd_src    = (const int*)d_in[2];
    const int* wd_dst    = (const int*)d_in[3];
    const int* td_src    = (const int*)d_in[4];
    const int* td_dst    = (const int*)d_in[5];
    const float* y_data  = (const float*)d_in[6];
    const float* wemb    = (const float*)d_in[7];
    const float* temb    = (const float*)d_in[8];
    const float* Wwd     = (const float*)d_in[9];
    const float* bwd     = (const float*)d_in[10];
    const float* Wtd     = (const float*)d_in[11];
    const float* btd     = (const float*)d_in[12];
    const float* Wout    = (const float*)d_in[13];
    const float* bout    = (const float*)d_in[14];
    float* out = (float*)d_out;
    unsigned* ws = (unsigned*)d_ws;

    f_v<<<1, HD, 0, stream>>>(Wwd, Wtd, Wout, ws);
    f_u<<<(NWORD + NTOPIC + 3) / 4, 256, 0, stream>>>(wemb, temb, ws);
    f_hist<<<NSW + NSD + NST, 1024, 0, stream>>>(wd_src, wd_dst, td_src, td_dst, ws);
    f_un<<<(NWN + NDOC + NTN + 255) / 256, 256, 0, stream>>>(word_ids, topic_ids, ws);
    f_edges<<<NBLK_E, 256, 0, stream>>>(wd_src, wd_dst, td_src, td_dst, ws);
    f_fin<<<1, HD, 0, stream>>>(y_data, bwd, btd, Wout, bout, ws, out);
}

// Round 20
// 63.840 us; speedup vs baseline: 3.2476x; 1.0106x over previous
//
#include <hip/hip_runtime.h>
#include <hip/hip_bf16.h>

#define NWN    100000
#define NTN    1600
#define NDOC   16384
#define EWD    1000000
#define ETD    200000
#define NWORD  15000
#define NTOPIC 50
#define HD     128
#define NB     32
#define NSW    64       // word-hist slabs (u8-packed)
#define NSD    64       // doc-hist slabs (u16-packed pairs)
#define NST    32       // topic-hist slabs
#define WRDW   25000    // u32 words holding 100000 u8 counters
#define NBLK_E 1172     // edge blocks: 300000 int4 units / 256 (= 4*293)

// ---- ws layout (u32 words), total 2,870,584 words = 11.5 MB ----
#define O_SLABW 0         // NSW*WRDW = 1600000
#define O_SLABD 1600000   // NSD*NDOC = 1048576
#define O_SLABT 2648576   // NST*NTN  = 51200
#define O_DOCS  2699776   // 16384 packed (wd lo16 | td hi16)
#define O_UNW   2716160   // 100000 f32
#define O_UNT   2816160   // 1600 f32
#define O_V     2817760   // 256 f32
#define O_UW    2818016   // 15000 f32
#define O_UT    2833016   // 64 f32
#define O_PART  2833080   // NBLK_E*NB = 37504 f32

// --- 1) all degree histograms, LDS-private, zero global atomics -------------
__global__ void __launch_bounds__(1024) f_hist(const int* __restrict__ wd_src,
                                               const int* __restrict__ wd_dst,
                                               const int* __restrict__ td_src,
                                               const int* __restrict__ td_dst,
                                               unsigned* __restrict__ ws) {
    __shared__ unsigned h[WRDW];          // 100 KB max (word role)
    int tid = threadIdx.x;
    int b   = blockIdx.x;
    if (b < NSW) {
        for (int k = tid; k < WRDW; k += 1024) h[k] = 0u;
        __syncthreads();
        const int4* p = (const int4*)wd_src;
        for (int i = b * 1024 + tid; i < EWD / 4; i += NSW * 1024) {
            int4 s = p[i];
            atomicAdd(&h[((unsigned)s.x) >> 2], 1u << (8 * (s.x & 3)));
            atomicAdd(&h[((unsigned)s.y) >> 2], 1u << (8 * (s.y & 3)));
            atomicAdd(&h[((unsigned)s.z) >> 2], 1u << (8 * (s.z & 3)));
            atomicAdd(&h[((unsigned)s.w) >> 2], 1u << (8 * (s.w & 3)));
        }
        __syncthreads();
        unsigned* slab = ws + O_SLABW + b * WRDW;
        for (int k = tid; k < WRDW; k += 1024) slab[k] = h[k];
    } else if (b < NSW + NSD) {
        int sb = b - NSW;
        for (int k = tid; k < NDOC; k += 1024) h[k] = 0u;
        __syncthreads();
        const int4* p = (const int4*)wd_dst;
        for (int i = sb * 1024 + tid; i < EWD / 4; i += NSD * 1024) {
            int4 d = p[i];
            atomicAdd(&h[d.x], 1u); atomicAdd(&h[d.y], 1u);
            atomicAdd(&h[d.z], 1u); atomicAdd(&h[d.w], 1u);
        }
        const int4* q = (const int4*)td_dst;
        for (int i = sb * 1024 + tid; i < ETD / 4; i += NSD * 1024) {
            int4 d = q[i];
            atomicAdd(&h[d.x], 65536u); atomicAdd(&h[d.y], 65536u);
            atomicAdd(&h[d.z], 65536u); atomicAdd(&h[d.w], 65536u);
        }
        __syncthreads();
        unsigned* slab = ws + O_SLABD + sb * NDOC;
        for (int k = tid; k < NDOC; k += 1024) slab[k] = h[k];
    } else {
        int sb = b - NSW - NSD;
        for (int k = tid; k < NTN; k += 1024) h[k] = 0u;
        __syncthreads();
        const int4* p = (const int4*)td_src;
        for (int i = sb * 1024 + tid; i < ETD / 4; i += NST * 1024) {
            int4 s = p[i];
            atomicAdd(&h[s.x], 1u); atomicAdd(&h[s.y], 1u);
            atomicAdd(&h[s.z], 1u); atomicAdd(&h[s.w], 1u);
        }
        __syncthreads();
        unsigned* slab = ws + O_SLABT + sb * NTN;
        for (int k = tid; k < NTN; k += 1024) slab[k] = h[k];
    }
}

// --- 2) v = [W_wd @ W_out | W_td @ W_out] -----------------------------------
__global__ void f_v(const float* __restrict__ Wwd, const float* __restrict__ Wtd,
                    const float* __restrict__ Wout, unsigned* __restrict__ ws) {
    __shared__ float wout[HD];
    int t = threadIdx.x;              // 128 threads
    float* v = (float*)(ws + O_V);
    wout[t] = Wout[t];
    __syncthreads();
    float s1 = 0.f, s2 = 0.f;
    for (int j = 0; j < HD; ++j) {
        s1 += Wwd[t * HD + j] * wout[j];
        s2 += Wtd[t * HD + j] * wout[j];
    }
    v[t]      = s1;
    v[t + HD] = s2;
}

// --- 3) u[row] = emb_row . v  (one wave per row) -----------------------------
__global__ void f_u(const float* __restrict__ wemb, const float* __restrict__ temb,
                    unsigned* __restrict__ ws) {
    const float* v = (const float*)(ws + O_V);
    int wave = threadIdx.x >> 6;
    int lane = threadIdx.x & 63;
    int row  = blockIdx.x * (blockDim.x >> 6) + wave;
    const float* src; const float* vv; float* dst; int r;
    if (row < NWORD) {
        src = wemb; vv = v; dst = (float*)(ws + O_UW); r = row;
    } else if (row < NWORD + NTOPIC) {
        src = temb; vv = v + HD; dst = (float*)(ws + O_UT); r = row - NWORD;
    } else return;
    float s = src[r * HD + lane]      * vv[lane]
            + src[r * HD + lane + 64] * vv[lane + 64];
    #pragma unroll
    for (int off = 32; off; off >>= 1) s += __shfl_down(s, off);
    if (lane == 0) dst[r] = s;
}

// --- 4) reduce slabs + fold outdeg norm + embedding gather ------------------
__global__ void f_un(const int* __restrict__ wids, const int* __restrict__ tids,
                     unsigned* __restrict__ ws) {
    const unsigned* slabW = ws + O_SLABW;
    const unsigned* slabD = ws + O_SLABD;
    const unsigned* slabT = ws + O_SLABT;
    unsigned* docs = ws + O_DOCS;
    const float* u_wd = (const float*)(ws + O_UW);
    const float* u_td = (const float*)(ws + O_UT);
    float* un_w = (float*)(ws + O_UNW);
    float* un_t = (float*)(ws + O_UNT);
    int t = blockIdx.x * blockDim.x + threadIdx.x;
    if (t < NWN) {
        int w = t >> 2, sh = 8 * (t & 3);
        unsigned d = 0u;
        #pragma unroll
        for (int j = 0; j < NSW; ++j) d += (slabW[j * WRDW + w] >> sh) & 0xFFu;
        un_w[t] = u_wd[wids[t]] * rsqrtf((float)(d > 1u ? d : 1u));
    } else if (t < NWN + NDOC) {
        int k = t - NWN;
        unsigned s = 0u;
        #pragma unroll
        for (int j = 0; j < NSD; ++j) s += slabD[j * NDOC + k];
        docs[k] = s;    // lo16/hi16 sums can't cross-carry
    } else if (t < NWN + NDOC + NTN) {
        int k = t - NWN - NDOC;
        unsigned d = 0u;
        #pragma unroll
        for (int j = 0; j < NST; ++j) d += slabT[j * NTN + k];
        un_t[k] = u_td[tids[k]] * rsqrtf((float)(d > 1u ? d : 1u));
    }
}

// --- 5) edges: one int4/thread, per-wave LDS acc, per-block partial store ---
__global__ void __launch_bounds__(256) f_edges(const int* __restrict__ wd_src,
                                               const int* __restrict__ wd_dst,
                                               const int* __restrict__ td_src,
                                               const int* __restrict__ td_dst,
                                               unsigned* __restrict__ ws) {
    const unsigned* docs = ws + O_DOCS;
    const float* un_w = (const float*)(ws + O_UNW);
    const float* un_t = (const float*)(ws + O_UNT);
    float* part = (float*)(ws + O_PART);
    __shared__ float lacc[4][NB];     // per-wave accumulators
    int tid  = threadIdx.x;
    int wv   = tid >> 6;
    if (tid < 4 * NB) ((float*)lacc)[tid] = 0.f;
    __syncthreads();
    float* wacc = lacc[wv];
    int u = blockIdx.x * 256 + tid;
    if (u < EWD / 4) {
        int4 s = ((const int4*)wd_src)[u];
        int4 d = ((const int4*)wd_dst)[u];
        unsigned b;
        b = docs[d.x] & 0xFFFFu;
        atomicAdd(&wacc[d.x >> 9], un_w[s.x] * rsqrtf((float)(b > 1u ? b : 1u)));
        b = docs[d.y] & 0xFFFFu;
        atomicAdd(&wacc[d.y >> 9], un_w[s.y] * rsqrtf((float)(b > 1u ? b : 1u)));
        b = docs[d.z] & 0xFFFFu;
        atomicAdd(&wacc[d.z >> 9], un_w[s.z] * rsqrtf((float)(b > 1u ? b : 1u)));
        b = docs[d.w] & 0xFFFFu;
        atomicAdd(&wacc[d.w >> 9], un_w[s.w] * rsqrtf((float)(b > 1u ? b : 1u)));
    } else if (u < EWD / 4 + ETD / 4) {
        int e = u - EWD / 4;
        int4 s = ((const int4*)td_src)[e];
        int4 d = ((const int4*)td_dst)[e];
        unsigned b;
        b = docs[d.x] >> 16;
        atomicAdd(&wacc[d.x >> 9], un_t[s.x] * rsqrtf((float)(b > 1u ? b : 1u)));
        b = docs[d.y] >> 16;
        atomicAdd(&wacc[d.y >> 9], un_t[s.y] * rsqrtf((float)(b > 1u ? b : 1u)));
        b = docs[d.z] >> 16;
        atomicAdd(&wacc[d.z >> 9], un_t[s.z] * rsqrtf((float)(b > 1u ? b : 1u)));
        b = docs[d.w] >> 16;
        atomicAdd(&wacc[d.w >> 9], un_t[s.w] * rsqrtf((float)(b > 1u ? b : 1u)));
    }
    __syncthreads();
    if (tid < NB)
        part[blockIdx.x * NB + tid] =
            lacc[0][tid] + lacc[1][tid] + lacc[2][tid] + lacc[3][tid];
}

// --- 6) finalize: reduce 1172x32 partials, c0, BCE loss, sigmoid ------------
__global__ void f_fin(const float* __restrict__ y_data,
                      const float* __restrict__ b_wd,
                      const float* __restrict__ b_td,
                      const float* __restrict__ Wout,
                      const float* __restrict__ b_out,
                      unsigned* __restrict__ ws,
                      float* __restrict__ out) {
    const float* part = (const float*)(ws + O_PART);
    __shared__ float quarter[4][NB];
    __shared__ float red[2];
    __shared__ float c0s;
    __shared__ float lsum[NB];
    int t = threadIdx.x;              // 128 threads
    int g = t & 31, q = t >> 5;
    float s = 0.f;
    for (int j = q * (NBLK_E / 4); j < (q + 1) * (NBLK_E / 4); ++j)
        s += part[j * NB + g];
    quarter[q][g] = s;
    float p = (b_wd[t] + b_td[t]) * Wout[t];
    #pragma unroll
    for (int off = 32; off; off >>= 1) p += __shfl_down(p, off);
    if ((t & 63) == 0) red[t >> 6] = p;
    __syncthreads();
    if (t == 0) c0s = red[0] + red[1] + b_out[0];
    __syncthreads();
    if (t < NB) {
        float acc = quarter[0][t] + quarter[1][t] + quarter[2][t] + quarter[3][t];
        float x = acc * (1.0f / 512.0f) + c0s;
        float y = y_data[t];
        lsum[t] = fmaxf(x, 0.f) - x * y + log1pf(expf(-fabsf(x)));
        out[1 + t] = 1.0f / (1.0f + expf(-x));
    }
    __syncthreads();
    if (t == 0) {
        float ss = 0.f;
        #pragma unroll
        for (int i = 0; i < NB; ++i) ss += lsum[i];
        out[0] = ss / (float)NB;
    }
}

extern "C" void kernel_launch(void* const* d_in, const int* in_sizes, int n_in,
                              void* d_out, int out_size, void* d_ws, size_t ws_size,
                              hipStream_t stream) {
    const int* word_ids  = (const int*)d_in[0];
    const int* topic_ids = (const int*)d_in[1];
    const int* wd_src    = (const int*)d_in[2];
    const int* wd_dst    = (const int*)d_in[3];
    const int* td_src    = (const int*)d_in[4];
    const int* td_dst    = (const int*)d_in[5];
    const float* y_data  = (const float*)d_in[6];
    const float* wemb    = (const float*)d_in[7];
    const float* temb    = (const float*)d_in[8];
    const float* Wwd     = (const float*)d_in[9];
    const float* bwd     = (const float*)d_in[10];
    const float* Wtd     = (const float*)d_in[11];
    const float* btd     = (const float*)d_in[12];
    const float* Wout    = (const float*)d_in[13];
    const float* bout    = (const float*)d_in[14];
    float* out = (float*)d_out;
    unsigned* ws = (unsigned*)d_ws;

    f_v<<<1, HD, 0, stream>>>(Wwd, Wtd, Wout, ws);
    f_u<<<(NWORD + NTOPIC + 3) / 4, 256, 0, stream>>>(wemb, temb, ws);
    f_hist<<<NSW + NSD + NST, 1024, 0, stream>>>(wd_src, wd_dst, td_src, td_dst, ws);
    f_un<<<(NWN + NDOC + NTN + 255) / 256, 256, 0, stream>>>(word_ids, topic_ids, ws);
    f_edges<<<NBLK_E, 256, 0, stream>>>(wd_src, wd_dst, td_src, td_dst, ws);
    f_fin<<<1, HD, 0, stream>>>(y_data, bwd, btd, Wout, bout, ws, out);
}

// Round 21
// 63.122 us; speedup vs baseline: 3.2845x; 1.0114x over previous
//
#include <hip/hip_runtime.h>
#include <hip/hip_bf16.h>

#define NWN    100000
#define NTN    1600
#define NDOC   16384
#define EWD    1000000
#define ETD    200000
#define NWORD  15000
#define NTOPIC 50
#define HD     128
#define NB     32
#define NSW    64       // word-hist slabs (u8-packed)
#define NSD    64       // doc-hist slabs (u16-packed pairs)
#define NST    32       // topic-hist slabs
#define WRDW   25000    // u32 words holding 100000 u8 counters
#define NBLK_E 1172     // edge blocks: 300000 int4 units / 256

// ---- ws layout (u32 words) ----
#define O_SLABW 0         // NSW*WRDW = 1600000
#define O_SLABD 1600000   // NSD*NDOC = 1048576
#define O_SLABT 2648576   // NST*NTN  = 51200
#define O_DOCS  2699776   // 16384 packed (wd lo16 | td hi16)
#define O_UNW   2716160   // 100000 f32
#define O_UNT   2816160   // 1600 f32
#define O_V     2817760   // 256 f32
#define O_UW    2818016   // 15000 f32
#define O_UT    2833016   // 64 f32
#define O_ACC   2833080   // 32 f32
#define O_CNT   2833112   // 8 u32

// --- 1) histograms (blocks 0..159) + v/acc/cnt init (block 160) -------------
__global__ void __launch_bounds__(1024) a_histv(const int* __restrict__ wd_src,
                                                const int* __restrict__ wd_dst,
                                                const int* __restrict__ td_src,
                                                const int* __restrict__ td_dst,
                                                const float* __restrict__ Wwd,
                                                const float* __restrict__ Wtd,
                                                const float* __restrict__ Wout,
                                                unsigned* __restrict__ ws) {
    __shared__ unsigned h[WRDW];          // 100 KB max (word role)
    int tid = threadIdx.x;
    int b   = blockIdx.x;
    if (b < NSW) {
        for (int k = tid; k < WRDW; k += 1024) h[k] = 0u;
        __syncthreads();
        const int4* p = (const int4*)wd_src;
        for (int i = b * 1024 + tid; i < EWD / 4; i += NSW * 1024) {
            int4 s = p[i];
            atomicAdd(&h[((unsigned)s.x) >> 2], 1u << (8 * (s.x & 3)));
            atomicAdd(&h[((unsigned)s.y) >> 2], 1u << (8 * (s.y & 3)));
            atomicAdd(&h[((unsigned)s.z) >> 2], 1u << (8 * (s.z & 3)));
            atomicAdd(&h[((unsigned)s.w) >> 2], 1u << (8 * (s.w & 3)));
        }
        __syncthreads();
        unsigned* slab = ws + O_SLABW + b * WRDW;
        for (int k = tid; k < WRDW; k += 1024) slab[k] = h[k];
    } else if (b < NSW + NSD) {
        int sb = b - NSW;
        for (int k = tid; k < NDOC; k += 1024) h[k] = 0u;
        __syncthreads();
        const int4* p = (const int4*)wd_dst;
        for (int i = sb * 1024 + tid; i < EWD / 4; i += NSD * 1024) {
            int4 d = p[i];
            atomicAdd(&h[d.x], 1u); atomicAdd(&h[d.y], 1u);
            atomicAdd(&h[d.z], 1u); atomicAdd(&h[d.w], 1u);
        }
        const int4* q = (const int4*)td_dst;
        for (int i = sb * 1024 + tid; i < ETD / 4; i += NSD * 1024) {
            int4 d = q[i];
            atomicAdd(&h[d.x], 65536u); atomicAdd(&h[d.y], 65536u);
            atomicAdd(&h[d.z], 65536u); atomicAdd(&h[d.w], 65536u);
        }
        __syncthreads();
        unsigned* slab = ws + O_SLABD + sb * NDOC;
        for (int k = tid; k < NDOC; k += 1024) slab[k] = h[k];
    } else if (b < NSW + NSD + NST) {
        int sb = b - NSW - NSD;
        for (int k = tid; k < NTN; k += 1024) h[k] = 0u;
        __syncthreads();
        const int4* p = (const int4*)td_src;
        for (int i = sb * 1024 + tid; i < ETD / 4; i += NST * 1024) {
            int4 s = p[i];
            atomicAdd(&h[s.x], 1u); atomicAdd(&h[s.y], 1u);
            atomicAdd(&h[s.z], 1u); atomicAdd(&h[s.w], 1u);
        }
        __syncthreads();
        unsigned* slab = ws + O_SLABT + sb * NTN;
        for (int k = tid; k < NTN; k += 1024) slab[k] = h[k];
    } else {
        // v = [W_wd @ W_out | W_td @ W_out]; zero acc + done-counter
        if (tid < HD) {
            float* hw = (float*)h;
            hw[tid] = Wout[tid];
            __syncthreads();
            float s1 = 0.f, s2 = 0.f;
            for (int j = 0; j < HD; ++j) {
                s1 += Wwd[tid * HD + j] * hw[j];
                s2 += Wtd[tid * HD + j] * hw[j];
            }
            float* v = (float*)(ws + O_V);
            v[tid]      = s1;
            v[tid + HD] = s2;
            if (tid < NB) ((float*)(ws + O_ACC))[tid] = 0.f;
            if (tid == NB) ws[O_CNT] = 0u;
        } else {
            __syncthreads();   // match the t<HD barrier
        }
    }
}

// --- 2) u[row] = emb_row . v  (one wave per row) -----------------------------
__global__ void f_u(const float* __restrict__ wemb, const float* __restrict__ temb,
                    unsigned* __restrict__ ws) {
    const float* v = (const float*)(ws + O_V);
    int wave = threadIdx.x >> 6;
    int lane = threadIdx.x & 63;
    int row  = blockIdx.x * (blockDim.x >> 6) + wave;
    const float* src; const float* vv; float* dst; int r;
    if (row < NWORD) {
        src = wemb; vv = v; dst = (float*)(ws + O_UW); r = row;
    } else if (row < NWORD + NTOPIC) {
        src = temb; vv = v + HD; dst = (float*)(ws + O_UT); r = row - NWORD;
    } else return;
    float s = src[r * HD + lane]      * vv[lane]
            + src[r * HD + lane + 64] * vv[lane + 64];
    #pragma unroll
    for (int off = 32; off; off >>= 1) s += __shfl_down(s, off);
    if (lane == 0) dst[r] = s;
}

// --- 3) reduce slabs + fold outdeg norm + embedding gather ------------------
__global__ void f_un(const int* __restrict__ wids, const int* __restrict__ tids,
                     unsigned* __restrict__ ws) {
    const unsigned* slabW = ws + O_SLABW;
    const unsigned* slabD = ws + O_SLABD;
    const unsigned* slabT = ws + O_SLABT;
    unsigned* docs = ws + O_DOCS;
    const float* u_wd = (const float*)(ws + O_UW);
    const float* u_td = (const float*)(ws + O_UT);
    float* un_w = (float*)(ws + O_UNW);
    float* un_t = (float*)(ws + O_UNT);
    int t = blockIdx.x * blockDim.x + threadIdx.x;
    if (t < NWN) {
        int w = t >> 2, sh = 8 * (t & 3);
        unsigned d = 0u;
        #pragma unroll
        for (int j = 0; j < NSW; ++j) d += (slabW[j * WRDW + w] >> sh) & 0xFFu;
        un_w[t] = u_wd[wids[t]] * rsqrtf((float)(d > 1u ? d : 1u));
    } else if (t < NWN + NDOC) {
        int k = t - NWN;
        unsigned s = 0u;
        #pragma unroll
        for (int j = 0; j < NSD; ++j) s += slabD[j * NDOC + k];
        docs[k] = s;
    } else if (t < NWN + NDOC + NTN) {
        int k = t - NWN - NDOC;
        unsigned d = 0u;
        #pragma unroll
        for (int j = 0; j < NST; ++j) d += slabT[j * NTN + k];
        un_t[k] = u_td[tids[k]] * rsqrtf((float)(d > 1u ? d : 1u));
    }
}

// --- 4) edges + last-block finalize (R18-proven pattern) --------------------
__global__ void __launch_bounds__(256) d_edges_fin(const int* __restrict__ wd_src,
                                                   const int* __restrict__ wd_dst,
                                                   const int* __restrict__ td_src,
                                                   const int* __restrict__ td_dst,
                                                   const float* __restrict__ y_data,
                                                   const float* __restrict__ b_wd,
                                                   const float* __restrict__ b_td,
                                                   const float* __restrict__ Wout,
                                                   const float* __restrict__ b_out,
                                                   unsigned* __restrict__ ws,
                                                   float* __restrict__ out) {
    const unsigned* docs = ws + O_DOCS;
    const float* un_w = (const float*)(ws + O_UNW);
    const float* un_t = (const float*)(ws + O_UNT);
    float* acc = (float*)(ws + O_ACC);
    __shared__ float lacc[4][NB];
    __shared__ unsigned lastflag;
    int tid = threadIdx.x;
    int wv  = tid >> 6;
    if (tid < 4 * NB) ((float*)lacc)[tid] = 0.f;
    __syncthreads();
    float* wacc = lacc[wv];
    int u = blockIdx.x * 256 + tid;
    if (u < EWD / 4) {
        int4 s = ((const int4*)wd_src)[u];
        int4 d = ((const int4*)wd_dst)[u];
        unsigned b;
        b = docs[d.x] & 0xFFFFu;
        atomicAdd(&wacc[d.x >> 9], un_w[s.x] * rsqrtf((float)(b > 1u ? b : 1u)));
        b = docs[d.y] & 0xFFFFu;
        atomicAdd(&wacc[d.y >> 9], un_w[s.y] * rsqrtf((float)(b > 1u ? b : 1u)));
        b = docs[d.z] & 0xFFFFu;
        atomicAdd(&wacc[d.z >> 9], un_w[s.z] * rsqrtf((float)(b > 1u ? b : 1u)));
        b = docs[d.w] & 0xFFFFu;
        atomicAdd(&wacc[d.w >> 9], un_w[s.w] * rsqrtf((float)(b > 1u ? b : 1u)));
    } else if (u < EWD / 4 + ETD / 4) {
        int e = u - EWD / 4;
        int4 s = ((const int4*)td_src)[e];
        int4 d = ((const int4*)td_dst)[e];
        unsigned b;
        b = docs[d.x] >> 16;
        atomicAdd(&wacc[d.x >> 9], un_t[s.x] * rsqrtf((float)(b > 1u ? b : 1u)));
        b = docs[d.y] >> 16;
        atomicAdd(&wacc[d.y >> 9], un_t[s.y] * rsqrtf((float)(b > 1u ? b : 1u)));
        b = docs[d.z] >> 16;
        atomicAdd(&wacc[d.z >> 9], un_t[s.z] * rsqrtf((float)(b > 1u ? b : 1u)));
        b = docs[d.w] >> 16;
        atomicAdd(&wacc[d.w >> 9], un_t[s.w] * rsqrtf((float)(b > 1u ? b : 1u)));
    }
    __syncthreads();
    if (tid < NB)
        atomicAdd(&acc[tid],
                  lacc[0][tid] + lacc[1][tid] + lacc[2][tid] + lacc[3][tid]);
    if (tid == 0) {
        __threadfence();
        unsigned prev = atomicAdd(&ws[O_CNT], 1u);
        lastflag = (prev == (unsigned)gridDim.x - 1u) ? 1u : 0u;
    }
    __syncthreads();
    if (lastflag && tid < 64) {
        float p = (b_wd[tid] + b_td[tid]) * Wout[tid]
                + (b_wd[tid + 64] + b_td[tid + 64]) * Wout[tid + 64];
        #pragma unroll
        for (int off = 32; off; off >>= 1) p += __shfl_down(p, off);
        float c0 = __shfl(p, 0) + b_out[0];
        float l = 0.f;
        if (tid < NB) {
            float a = atomicAdd(&acc[tid], 0.0f);   // coherent read
            float x = a * (1.0f / 512.0f) + c0;
            float y = y_data[tid];
            l = fmaxf(x, 0.f) - x * y + log1pf(expf(-fabsf(x)));
            out[1 + tid] = 1.0f / (1.0f + expf(-x));
        }
        #pragma unroll
        for (int off = 16; off; off >>= 1) l += __shfl_down(l, off);
        if (tid == 0) out[0] = l * (1.0f / (float)NB);
    }
}

extern "C" void kernel_launch(void* const* d_in, const int* in_sizes, int n_in,
                              void* d_out, int out_size, void* d_ws, size_t ws_size,
                              hipStream_t stream) {
    const int* word_ids  = (const int*)d_in[0];
    const int* topic_ids = (const int*)d_in[1];
    const int* wd_src    = (const int*)d_in[2];
    const int* wd_dst    = (const int*)d_in[3];
    const int* td_src    = (const int*)d_in[4];
    const int* td_dst    = (const int*)d_in[5];
    const float* y_data  = (const float*)d_in[6];
    const float* wemb    = (const float*)d_in[7];
    const float* temb    = (const float*)d_in[8];
    const float* Wwd     = (const float*)d_in[9];
    const float* bwd     = (const float*)d_in[10];
    const float* Wtd     = (const float*)d_in[11];
    const float* btd     = (const float*)d_in[12];
    const float* Wout    = (const float*)d_in[13];
    const float* bout    = (const float*)d_in[14];
    float* out = (float*)d_out;
    unsigned* ws = (unsigned*)d_ws;

    a_histv<<<NSW + NSD + NST + 1, 1024, 0, stream>>>(
        wd_src, wd_dst, td_src, td_dst, Wwd, Wtd, Wout, ws);
    f_u<<<(NWORD + NTOPIC + 3) / 4, 256, 0, stream>>>(wemb, temb, ws);
    f_un<<<(NWN + NDOC + NTN + 255) / 256, 256, 0, stream>>>(word_ids, topic_ids, ws);
    d_edges_fin<<<NBLK_E, 256, 0, stream>>>(wd_src, wd_dst, td_src, td_dst,
                                            y_data, bwd, btd, Wout, bout, ws, out);
}

// Round 22
// 42.623 us; speedup vs baseline: 4.8641x; 1.4809x over previous
//
#include <hip/hip_runtime.h>
#include <hip/hip_bf16.h>

#define NWN    100000
#define NTN    1600
#define NDOC   16384
#define EWD    1000000
#define ETD    200000
#define NWORD  15000
#define NTOPIC 50
#define HD     128
#define NB     32
#define NSW    64       // word-hist slabs (u8-packed)
#define NSD    64       // doc-hist slabs (u16-packed pairs)
#define NST    32       // topic-hist slabs
#define WRDW   25000    // u32 words holding 100000 u8 counters
#define NBLK_E 293      // edge blocks: 4 int4-units per thread
#define NTHR_E (NBLK_E * 256)   // 75008 threads

// ---- ws layout (u32 words) ----
#define O_SLABW 0         // NSW*WRDW = 1600000
#define O_SLABD 1600000   // NSD*NDOC = 1048576
#define O_SLABT 2648576   // NST*NTN  = 51200
#define O_DOCS  2699776   // 16384 packed (wd lo16 | td hi16)
#define O_UNW   2716160   // 100000 f32
#define O_UNT   2816160   // 1600 f32
#define O_V     2817760   // 256 f32
#define O_UW    2818016   // 15000 f32
#define O_UT    2833016   // 64 f32
#define O_ACC   2833080   // 32 f32
#define O_CNT   2833112   // 8 u32

// --- 1) histograms (blocks 0..159) + v/acc/cnt init (block 160) -------------
__global__ void __launch_bounds__(1024) a_histv(const int* __restrict__ wd_src,
                                                const int* __restrict__ wd_dst,
                                                const int* __restrict__ td_src,
                                                const int* __restrict__ td_dst,
                                                const float* __restrict__ Wwd,
                                                const float* __restrict__ Wtd,
                                                const float* __restrict__ Wout,
                                                unsigned* __restrict__ ws) {
    __shared__ unsigned h[WRDW];          // 100 KB max (word role)
    int tid = threadIdx.x;
    int b   = blockIdx.x;
    if (b < NSW) {
        for (int k = tid; k < WRDW; k += 1024) h[k] = 0u;
        __syncthreads();
        const int4* p = (const int4*)wd_src;
        for (int i = b * 1024 + tid; i < EWD / 4; i += NSW * 1024) {
            int4 s = p[i];
            atomicAdd(&h[((unsigned)s.x) >> 2], 1u << (8 * (s.x & 3)));
            atomicAdd(&h[((unsigned)s.y) >> 2], 1u << (8 * (s.y & 3)));
            atomicAdd(&h[((unsigned)s.z) >> 2], 1u << (8 * (s.z & 3)));
            atomicAdd(&h[((unsigned)s.w) >> 2], 1u << (8 * (s.w & 3)));
        }
        __syncthreads();
        unsigned* slab = ws + O_SLABW + b * WRDW;
        for (int k = tid; k < WRDW; k += 1024) slab[k] = h[k];
    } else if (b < NSW + NSD) {
        int sb = b - NSW;
        for (int k = tid; k < NDOC; k += 1024) h[k] = 0u;
        __syncthreads();
        const int4* p = (const int4*)wd_dst;
        for (int i = sb * 1024 + tid; i < EWD / 4; i += NSD * 1024) {
            int4 d = p[i];
            atomicAdd(&h[d.x], 1u); atomicAdd(&h[d.y], 1u);
            atomicAdd(&h[d.z], 1u); atomicAdd(&h[d.w], 1u);
        }
        const int4* q = (const int4*)td_dst;
        for (int i = sb * 1024 + tid; i < ETD / 4; i += NSD * 1024) {
            int4 d = q[i];
            atomicAdd(&h[d.x], 65536u); atomicAdd(&h[d.y], 65536u);
            atomicAdd(&h[d.z], 65536u); atomicAdd(&h[d.w], 65536u);
        }
        __syncthreads();
        unsigned* slab = ws + O_SLABD + sb * NDOC;
        for (int k = tid; k < NDOC; k += 1024) slab[k] = h[k];
    } else if (b < NSW + NSD + NST) {
        int sb = b - NSW - NSD;
        for (int k = tid; k < NTN; k += 1024) h[k] = 0u;
        __syncthreads();
        const int4* p = (const int4*)td_src;
        for (int i = sb * 1024 + tid; i < ETD / 4; i += NST * 1024) {
            int4 s = p[i];
            atomicAdd(&h[s.x], 1u); atomicAdd(&h[s.y], 1u);
            atomicAdd(&h[s.z], 1u); atomicAdd(&h[s.w], 1u);
        }
        __syncthreads();
        unsigned* slab = ws + O_SLABT + sb * NTN;
        for (int k = tid; k < NTN; k += 1024) slab[k] = h[k];
    } else {
        // v = [W_wd @ W_out | W_td @ W_out]; zero acc + done-counter
        if (tid < HD) {
            float* hw = (float*)h;
            hw[tid] = Wout[tid];
            __syncthreads();
            float s1 = 0.f, s2 = 0.f;
            for (int j = 0; j < HD; ++j) {
                s1 += Wwd[tid * HD + j] * hw[j];
                s2 += Wtd[tid * HD + j] * hw[j];
            }
            float* v = (float*)(ws + O_V);
            v[tid]      = s1;
            v[tid + HD] = s2;
            if (tid < NB) ((float*)(ws + O_ACC))[tid] = 0.f;
            if (tid == NB) ws[O_CNT] = 0u;
        } else {
            __syncthreads();   // match the t<HD barrier
        }
    }
}

// --- 2) u[row] = emb_row . v  (one wave per row) -----------------------------
__global__ void f_u(const float* __restrict__ wemb, const float* __restrict__ temb,
                    unsigned* __restrict__ ws) {
    const float* v = (const float*)(ws + O_V);
    int wave = threadIdx.x >> 6;
    int lane = threadIdx.x & 63;
    int row  = blockIdx.x * (blockDim.x >> 6) + wave;
    const float* src; const float* vv; float* dst; int r;
    if (row < NWORD) {
        src = wemb; vv = v; dst = (float*)(ws + O_UW); r = row;
    } else if (row < NWORD + NTOPIC) {
        src = temb; vv = v + HD; dst = (float*)(ws + O_UT); r = row - NWORD;
    } else return;
    float s = src[r * HD + lane]      * vv[lane]
            + src[r * HD + lane + 64] * vv[lane + 64];
    #pragma unroll
    for (int off = 32; off; off >>= 1) s += __shfl_down(s, off);
    if (lane == 0) dst[r] = s;
}

// --- 3) reduce slabs + fold outdeg norm + embedding gather ------------------
__global__ void f_un(const int* __restrict__ wids, const int* __restrict__ tids,
                     unsigned* __restrict__ ws) {
    const unsigned* slabW = ws + O_SLABW;
    const unsigned* slabD = ws + O_SLABD;
    const unsigned* slabT = ws + O_SLABT;
    unsigned* docs = ws + O_DOCS;
    const float* u_wd = (const float*)(ws + O_UW);
    const float* u_td = (const float*)(ws + O_UT);
    float* un_w = (float*)(ws + O_UNW);
    float* un_t = (float*)(ws + O_UNT);
    int t = blockIdx.x * blockDim.x + threadIdx.x;
    if (t < NWN) {
        int w = t >> 2, sh = 8 * (t & 3);
        unsigned d = 0u;
        #pragma unroll
        for (int j = 0; j < NSW; ++j) d += (slabW[j * WRDW + w] >> sh) & 0xFFu;
        un_w[t] = u_wd[wids[t]] * rsqrtf((float)(d > 1u ? d : 1u));
    } else if (t < NWN + NDOC) {
        int k = t - NWN;
        unsigned s = 0u;
        #pragma unroll
        for (int j = 0; j < NSD; ++j) s += slabD[j * NDOC + k];
        docs[k] = s;
    } else if (t < NWN + NDOC + NTN) {
        int k = t - NWN - NDOC;
        unsigned d = 0u;
        #pragma unroll
        for (int j = 0; j < NST; ++j) d += slabT[j * NTN + k];
        un_t[k] = u_td[tids[k]] * rsqrtf((float)(d > 1u ? d : 1u));
    }
}

// --- 4) edges (4 int4-units/thread, deep MLP) + last-block finalize ---------
__global__ void __launch_bounds__(256) d_edges_fin(const int* __restrict__ wd_src,
                                                   const int* __restrict__ wd_dst,
                                                   const int* __restrict__ td_src,
                                                   const int* __restrict__ td_dst,
                                                   const float* __restrict__ y_data,
                                                   const float* __restrict__ b_wd,
                                                   const float* __restrict__ b_td,
                                                   const float* __restrict__ Wout,
                                                   const float* __restrict__ b_out,
                                                   unsigned* __restrict__ ws,
                                                   float* __restrict__ out) {
    const unsigned* docs = ws + O_DOCS;
    const float* un_w = (const float*)(ws + O_UNW);
    const float* un_t = (const float*)(ws + O_UNT);
    float* acc = (float*)(ws + O_ACC);
    __shared__ float lacc[4][NB];
    __shared__ unsigned lastflag;
    int tid = threadIdx.x;
    int wv  = tid >> 6;
    if (tid < 4 * NB) ((float*)lacc)[tid] = 0.f;
    __syncthreads();
    float* wacc = lacc[wv];

    // phase 1: issue all stream loads (independent)
    int4 sv[4], dv[4];
    int kind[4];
    int base = blockIdx.x * 256 + tid;
    #pragma unroll
    for (int k = 0; k < 4; ++k) {
        int u = base + k * NTHR_E;
        if (u < EWD / 4) {
            sv[k] = ((const int4*)wd_src)[u];
            dv[k] = ((const int4*)wd_dst)[u];
            kind[k] = 0;
        } else if (u < (EWD + ETD) / 4) {
            int e = u - EWD / 4;
            sv[k] = ((const int4*)td_src)[e];
            dv[k] = ((const int4*)td_dst)[e];
            kind[k] = 1;
        } else {
            kind[k] = 2;
        }
    }
    // phase 2: gathers (32 independent loads across units) + LDS accumulate
    #pragma unroll
    for (int k = 0; k < 4; ++k) {
        int4 s = sv[k], d = dv[k];
        unsigned b;
        if (kind[k] == 0) {
            b = docs[d.x] & 0xFFFFu;
            atomicAdd(&wacc[d.x >> 9], un_w[s.x] * rsqrtf((float)(b > 1u ? b : 1u)));
            b = docs[d.y] & 0xFFFFu;
            atomicAdd(&wacc[d.y >> 9], un_w[s.y] * rsqrtf((float)(b > 1u ? b : 1u)));
            b = docs[d.z] & 0xFFFFu;
            atomicAdd(&wacc[d.z >> 9], un_w[s.z] * rsqrtf((float)(b > 1u ? b : 1u)));
            b = docs[d.w] & 0xFFFFu;
            atomicAdd(&wacc[d.w >> 9], un_w[s.w] * rsqrtf((float)(b > 1u ? b : 1u)));
        } else if (kind[k] == 1) {
            b = docs[d.x] >> 16;
            atomicAdd(&wacc[d.x >> 9], un_t[s.x] * rsqrtf((float)(b > 1u ? b : 1u)));
            b = docs[d.y] >> 16;
            atomicAdd(&wacc[d.y >> 9], un_t[s.y] * rsqrtf((float)(b > 1u ? b : 1u)));
            b = docs[d.z] >> 16;
            atomicAdd(&wacc[d.z >> 9], un_t[s.z] * rsqrtf((float)(b > 1u ? b : 1u)));
            b = docs[d.w] >> 16;
            atomicAdd(&wacc[d.w >> 9], un_t[s.w] * rsqrtf((float)(b > 1u ? b : 1u)));
        }
    }
    __syncthreads();
    if (tid < NB)
        atomicAdd(&acc[tid],
                  lacc[0][tid] + lacc[1][tid] + lacc[2][tid] + lacc[3][tid]);
    if (tid == 0) {
        __threadfence();
        unsigned prev = atomicAdd(&ws[O_CNT], 1u);
        lastflag = (prev == (unsigned)gridDim.x - 1u) ? 1u : 0u;
    }
    __syncthreads();
    if (lastflag && tid < 64) {
        float p = (b_wd[tid] + b_td[tid]) * Wout[tid]
                + (b_wd[tid + 64] + b_td[tid + 64]) * Wout[tid + 64];
        #pragma unroll
        for (int off = 32; off; off >>= 1) p += __shfl_down(p, off);
        float c0 = __shfl(p, 0) + b_out[0];
        float l = 0.f;
        if (tid < NB) {
            float a = atomicAdd(&acc[tid], 0.0f);   // coherent read
            float x = a * (1.0f / 512.0f) + c0;
            float y = y_data[tid];
            l = fmaxf(x, 0.f) - x * y + log1pf(expf(-fabsf(x)));
            out[1 + tid] = 1.0f / (1.0f + expf(-x));
        }
        #pragma unroll
        for (int off = 16; off; off >>= 1) l += __shfl_down(l, off);
        if (tid == 0) out[0] = l * (1.0f / (float)NB);
    }
}

extern "C" void kernel_launch(void* const* d_in, const int* in_sizes, int n_in,
                              void* d_out, int out_size, void* d_ws, size_t ws_size,
                              hipStream_t stream) {
    const int* word_ids  = (const int*)d_in[0];
    const int* topic_ids = (const int*)d_in[1];
    const int* wd_src    = (const int*)d_in[2];
    const int* wd_dst    = (const int*)d_in[3];
    const int* td_src    = (const int*)d_in[4];
    const int* td_dst    = (const int*)d_in[5];
    const float* y_data  = (const float*)d_in[6];
    const float* wemb    = (const float*)d_in[7];
    const float* temb    = (const float*)d_in[8];
    const float* Wwd     = (const float*)d_in[9];
    const float* bwd     = (const float*)d_in[10];
    const float* Wtd     = (const float*)d_in[11];
    const float* btd     = (const float*)d_in[12];
    const float* Wout    = (const float*)d_in[13];
    const float* bout    = (const float*)d_in[14];
    float* out = (float*)d_out;
    unsigned* ws = (unsigned*)d_ws;

    a_histv<<<NSW + NSD + NST + 1, 1024, 0, stream>>>(
        wd_src, wd_dst, td_src, td_dst, Wwd, Wtd, Wout, ws);
    f_u<<<(NWORD + NTOPIC + 3) / 4, 256, 0, stream>>>(wemb, temb, ws);
    f_un<<<(NWN + NDOC + NTN + 255) / 256, 256, 0, stream>>>(word_ids, topic_ids, ws);
    d_edges_fin<<<NBLK_E, 256, 0, stream>>>(wd_src, wd_dst, td_src, td_dst,
                                            y_data, bwd, btd, Wout, bout, ws, out);
}

// Round 23
// 39.441 us; speedup vs baseline: 5.2566x; 1.0807x over previous
//
#include <hip/hip_runtime.h>
#include <hip/hip_bf16.h>

#define NWN    100000
#define NTN    1600
#define NDOC   16384
#define EWD    1000000
#define ETD    200000
#define NWORD  15000
#define NTOPIC 50
#define HD     128
#define NB     32
#define NSW    64       // word-hist slabs (u8-packed)
#define NSD    64       // doc-hist slabs (u16-packed pairs)
#define NST    32       // topic-hist slabs
#define WRDW   25000    // u32 words holding 100000 u8 counters
#define NBLK_E 256      // edge blocks: one per CU
#define BDIM_E 640      // 10 waves/block
#define STRIDE_E (NBLK_E * BDIM_E)   // 163840 threads
#define NU4    300000   // total int4 units: EWD/4 + ETD/4
#define NWAVE_E (BDIM_E / 64)        // 10

// ---- ws layout (u32 words) ----
#define O_SLABW 0         // NSW*WRDW = 1600000
#define O_SLABD 1600000   // NSD*NDOC = 1048576
#define O_SLABT 2648576   // NST*NTN  = 51200
#define O_DOCS  2699776   // 16384 packed (wd lo16 | td hi16)
#define O_UNW   2716160   // 100000 f32
#define O_UNT   2816160   // 1600 f32
#define O_V     2817760   // 256 f32
#define O_UW    2818016   // 15000 f32
#define O_UT    2833016   // 64 f32
#define O_ACC   2833080   // 32 f32
#define O_CNT   2833112   // 8 u32

// --- 1) histograms (blocks 0..159) + v/acc/cnt init (block 160) -------------
__global__ void __launch_bounds__(1024) a_histv(const int* __restrict__ wd_src,
                                                const int* __restrict__ wd_dst,
                                                const int* __restrict__ td_src,
                                                const int* __restrict__ td_dst,
                                                const float* __restrict__ Wwd,
                                                const float* __restrict__ Wtd,
                                                const float* __restrict__ Wout,
                                                unsigned* __restrict__ ws) {
    __shared__ unsigned h[WRDW];          // 100 KB max (word role)
    int tid = threadIdx.x;
    int b   = blockIdx.x;
    if (b < NSW) {
        for (int k = tid; k < WRDW; k += 1024) h[k] = 0u;
        __syncthreads();
        const int4* p = (const int4*)wd_src;
        for (int i = b * 1024 + tid; i < EWD / 4; i += NSW * 1024) {
            int4 s = p[i];
            atomicAdd(&h[((unsigned)s.x) >> 2], 1u << (8 * (s.x & 3)));
            atomicAdd(&h[((unsigned)s.y) >> 2], 1u << (8 * (s.y & 3)));
            atomicAdd(&h[((unsigned)s.z) >> 2], 1u << (8 * (s.z & 3)));
            atomicAdd(&h[((unsigned)s.w) >> 2], 1u << (8 * (s.w & 3)));
        }
        __syncthreads();
        unsigned* slab = ws + O_SLABW + b * WRDW;
        for (int k = tid; k < WRDW; k += 1024) slab[k] = h[k];
    } else if (b < NSW + NSD) {
        int sb = b - NSW;
        for (int k = tid; k < NDOC; k += 1024) h[k] = 0u;
        __syncthreads();
        const int4* p = (const int4*)wd_dst;
        for (int i = sb * 1024 + tid; i < EWD / 4; i += NSD * 1024) {
            int4 d = p[i];
            atomicAdd(&h[d.x], 1u); atomicAdd(&h[d.y], 1u);
            atomicAdd(&h[d.z], 1u); atomicAdd(&h[d.w], 1u);
        }
        const int4* q = (const int4*)td_dst;
        for (int i = sb * 1024 + tid; i < ETD / 4; i += NSD * 1024) {
            int4 d = q[i];
            atomicAdd(&h[d.x], 65536u); atomicAdd(&h[d.y], 65536u);
            atomicAdd(&h[d.z], 65536u); atomicAdd(&h[d.w], 65536u);
        }
        __syncthreads();
        unsigned* slab = ws + O_SLABD + sb * NDOC;
        for (int k = tid; k < NDOC; k += 1024) slab[k] = h[k];
    } else if (b < NSW + NSD + NST) {
        int sb = b - NSW - NSD;
        for (int k = tid; k < NTN; k += 1024) h[k] = 0u;
        __syncthreads();
        const int4* p = (const int4*)td_src;
        for (int i = sb * 1024 + tid; i < ETD / 4; i += NST * 1024) {
            int4 s = p[i];
            atomicAdd(&h[s.x], 1u); atomicAdd(&h[s.y], 1u);
            atomicAdd(&h[s.z], 1u); atomicAdd(&h[s.w], 1u);
        }
        __syncthreads();
        unsigned* slab = ws + O_SLABT + sb * NTN;
        for (int k = tid; k < NTN; k += 1024) slab[k] = h[k];
    } else {
        // v = [W_wd @ W_out | W_td @ W_out]; zero acc + done-counter
        if (tid < HD) {
            float* hw = (float*)h;
            hw[tid] = Wout[tid];
            __syncthreads();
            float s1 = 0.f, s2 = 0.f;
            for (int j = 0; j < HD; ++j) {
                s1 += Wwd[tid * HD + j] * hw[j];
                s2 += Wtd[tid * HD + j] * hw[j];
            }
            float* v = (float*)(ws + O_V);
            v[tid]      = s1;
            v[tid + HD] = s2;
            if (tid < NB) ((float*)(ws + O_ACC))[tid] = 0.f;
            if (tid == NB) ws[O_CNT] = 0u;
        } else {
            __syncthreads();   // match the t<HD barrier
        }
    }
}

// --- 2) u[row] = emb_row . v  (one wave per row) -----------------------------
__global__ void f_u(const float* __restrict__ wemb, const float* __restrict__ temb,
                    unsigned* __restrict__ ws) {
    const float* v = (const float*)(ws + O_V);
    int wave = threadIdx.x >> 6;
    int lane = threadIdx.x & 63;
    int row  = blockIdx.x * (blockDim.x >> 6) + wave;
    const float* src; const float* vv; float* dst; int r;
    if (row < NWORD) {
        src = wemb; vv = v; dst = (float*)(ws + O_UW); r = row;
    } else if (row < NWORD + NTOPIC) {
        src = temb; vv = v + HD; dst = (float*)(ws + O_UT); r = row - NWORD;
    } else return;
    float s = src[r * HD + lane]      * vv[lane]
            + src[r * HD + lane + 64] * vv[lane + 64];
    #pragma unroll
    for (int off = 32; off; off >>= 1) s += __shfl_down(s, off);
    if (lane == 0) dst[r] = s;
}

// --- 3) reduce slabs + fold outdeg norm + embedding gather ------------------
__global__ void f_un(const int* __restrict__ wids, const int* __restrict__ tids,
                     unsigned* __restrict__ ws) {
    const unsigned* slabW = ws + O_SLABW;
    const unsigned* slabD = ws + O_SLABD;
    const unsigned* slabT = ws + O_SLABT;
    unsigned* docs = ws + O_DOCS;
    const float* u_wd = (const float*)(ws + O_UW);
    const float* u_td = (const float*)(ws + O_UT);
    float* un_w = (float*)(ws + O_UNW);
    float* un_t = (float*)(ws + O_UNT);
    int t = blockIdx.x * blockDim.x + threadIdx.x;
    if (t < NWN) {
        int w = t >> 2, sh = 8 * (t & 3);
        unsigned d = 0u;
        #pragma unroll
        for (int j = 0; j < NSW; ++j) d += (slabW[j * WRDW + w] >> sh) & 0xFFu;
        un_w[t] = u_wd[wids[t]] * rsqrtf((float)(d > 1u ? d : 1u));
    } else if (t < NWN + NDOC) {
        int k = t - NWN;
        unsigned s = 0u;
        #pragma unroll
        for (int j = 0; j < NSD; ++j) s += slabD[j * NDOC + k];
        docs[k] = s;
    } else if (t < NWN + NDOC + NTN) {
        int k = t - NWN - NDOC;
        unsigned d = 0u;
        #pragma unroll
        for (int j = 0; j < NST; ++j) d += slabT[j * NTN + k];
        un_t[k] = u_td[tids[k]] * rsqrtf((float)(d > 1u ? d : 1u));
    }
}

// --- 4) edges: 256 blocks x 640 thr (10 waves/CU), 2 units/thread, + fin ----
__global__ void __launch_bounds__(BDIM_E) d_edges_fin(const int* __restrict__ wd_src,
                                                      const int* __restrict__ wd_dst,
                                                      const int* __restrict__ td_src,
                                                      const int* __restrict__ td_dst,
                                                      const float* __restrict__ y_data,
                                                      const float* __restrict__ b_wd,
                                                      const float* __restrict__ b_td,
                                                      const float* __restrict__ Wout,
                                                      const float* __restrict__ b_out,
                                                      unsigned* __restrict__ ws,
                                                      float* __restrict__ out) {
    const unsigned* docs = ws + O_DOCS;
    const float* un_w = (const float*)(ws + O_UNW);
    const float* un_t = (const float*)(ws + O_UNT);
    float* acc = (float*)(ws + O_ACC);
    __shared__ float lacc[NWAVE_E][NB];
    __shared__ unsigned lastflag;
    int tid = threadIdx.x;
    int wv  = tid >> 6;
    if (tid < NWAVE_E * NB) ((float*)lacc)[tid] = 0.f;
    __syncthreads();
    float* wacc = lacc[wv];

    // phase 1: stage both units' stream loads (independent)
    int4 sv[2], dv[2];
    int kind[2];
    int gid = blockIdx.x * BDIM_E + tid;
    #pragma unroll
    for (int k = 0; k < 2; ++k) {
        int u = gid + k * STRIDE_E;
        if (u < EWD / 4) {
            sv[k] = ((const int4*)wd_src)[u];
            dv[k] = ((const int4*)wd_dst)[u];
            kind[k] = 0;
        } else if (u < NU4) {
            int e = u - EWD / 4;
            sv[k] = ((const int4*)td_src)[e];
            dv[k] = ((const int4*)td_dst)[e];
            kind[k] = 1;
        } else {
            kind[k] = 2;
        }
    }
    // phase 2: 16 independent gathers + LDS accumulate
    #pragma unroll
    for (int k = 0; k < 2; ++k) {
        int4 s = sv[k], d = dv[k];
        unsigned b;
        if (kind[k] == 0) {
            b = docs[d.x] & 0xFFFFu;
            atomicAdd(&wacc[d.x >> 9], un_w[s.x] * rsqrtf((float)(b > 1u ? b : 1u)));
            b = docs[d.y] & 0xFFFFu;
            atomicAdd(&wacc[d.y >> 9], un_w[s.y] * rsqrtf((float)(b > 1u ? b : 1u)));
            b = docs[d.z] & 0xFFFFu;
            atomicAdd(&wacc[d.z >> 9], un_w[s.z] * rsqrtf((float)(b > 1u ? b : 1u)));
            b = docs[d.w] & 0xFFFFu;
            atomicAdd(&wacc[d.w >> 9], un_w[s.w] * rsqrtf((float)(b > 1u ? b : 1u)));
        } else if (kind[k] == 1) {
            b = docs[d.x] >> 16;
            atomicAdd(&wacc[d.x >> 9], un_t[s.x] * rsqrtf((float)(b > 1u ? b : 1u)));
            b = docs[d.y] >> 16;
            atomicAdd(&wacc[d.y >> 9], un_t[s.y] * rsqrtf((float)(b > 1u ? b : 1u)));
            b = docs[d.z] >> 16;
            atomicAdd(&wacc[d.z >> 9], un_t[s.z] * rsqrtf((float)(b > 1u ? b : 1u)));
            b = docs[d.w] >> 16;
            atomicAdd(&wacc[d.w >> 9], un_t[s.w] * rsqrtf((float)(b > 1u ? b : 1u)));
        }
    }
    __syncthreads();
    if (tid < NB) {
        float s = 0.f;
        #pragma unroll
        for (int j = 0; j < NWAVE_E; ++j) s += lacc[j][tid];
        atomicAdd(&acc[tid], s);
    }
    if (tid == 0) {
        __threadfence();
        unsigned prev = atomicAdd(&ws[O_CNT], 1u);
        lastflag = (prev == (unsigned)gridDim.x - 1u) ? 1u : 0u;
    }
    __syncthreads();
    if (lastflag && tid < 64) {
        float p = (b_wd[tid] + b_td[tid]) * Wout[tid]
                + (b_wd[tid + 64] + b_td[tid + 64]) * Wout[tid + 64];
        #pragma unroll
        for (int off = 32; off; off >>= 1) p += __shfl_down(p, off);
        float c0 = __shfl(p, 0) + b_out[0];
        float l = 0.f;
        if (tid < NB) {
            float a = atomicAdd(&acc[tid], 0.0f);   // coherent read
            float x = a * (1.0f / 512.0f) + c0;
            float y = y_data[tid];
            l = fmaxf(x, 0.f) - x * y + log1pf(expf(-fabsf(x)));
            out[1 + tid] = 1.0f / (1.0f + expf(-x));
        }
        #pragma unroll
        for (int off = 16; off; off >>= 1) l += __shfl_down(l, off);
        if (tid == 0) out[0] = l * (1.0f / (float)NB);
    }
}

extern "C" void kernel_launch(void* const* d_in, const int* in_sizes, int n_in,
                              void* d_out, int out_size, void* d_ws, size_t ws_size,
                              hipStream_t stream) {
    const int* word_ids  = (const int*)d_in[0];
    const int* topic_ids = (const int*)d_in[1];
    const int* wd_src    = (const int*)d_in[2];
    const int* wd_dst    = (const int*)d_in[3];
    const int* td_src    = (const int*)d_in[4];
    const int* td_dst    = (const int*)d_in[5];
    const float* y_data  = (const float*)d_in[6];
    const float* wemb    = (const float*)d_in[7];
    const float* temb    = (const float*)d_in[8];
    const float* Wwd     = (const float*)d_in[9];
    const float* bwd     = (const float*)d_in[10];
    const float* Wtd     = (const float*)d_in[11];
    const float* btd     = (const float*)d_in[12];
    const float* Wout    = (const float*)d_in[13];
    const float* bout    = (const float*)d_in[14];
    float* out = (float*)d_out;
    unsigned* ws = (unsigned*)d_ws;

    a_histv<<<NSW + NSD + NST + 1, 1024, 0, stream>>>(
        wd_src, wd_dst, td_src, td_dst, Wwd, Wtd, Wout, ws);
    f_u<<<(NWORD + NTOPIC + 3) / 4, 256, 0, stream>>>(wemb, temb, ws);
    f_un<<<(NWN + NDOC + NTN + 255) / 256, 256, 0, stream>>>(word_ids, topic_ids, ws);
    d_edges_fin<<<NBLK_E, BDIM_E, 0, stream>>>(wd_src, wd_dst, td_src, td_dst,
                                               y_data, bwd, btd, Wout, bout, ws, out);
}